// Round 1
// baseline (6815.744 us; speedup 1.0000x reference)
//
#include <hip/hip_runtime.h>
#include <hip/hip_bf16.h>
#include <float.h>

#define BATCH 8
#define TPTS 30000
#define HID 128
#define R2 4096
#define NPTS (BATCH * TPTS)   // 240000

// ---------- helpers ----------

__device__ inline void atomicMaxF(float* addr, float v) {
    // float max via monotone int bit tricks (works with mixed signs, init -FLT_MAX)
    if (v >= 0.f) atomicMax((int*)addr, __float_as_int(v));
    else          atomicMin((unsigned int*)addr, __float_as_uint(v));
}

__global__ void k_fill4(float4* p, float v, int n4) {
    int i = blockIdx.x * blockDim.x + threadIdx.x;
    if (i < n4) p[i] = make_float4(v, v, v, v);
}

// ---------- fused fc_pos + resnet block 0 ----------
// x = points @ Wp + bp  (built in LDS, never materialized globally)
// net0 = relu(x)@w0+b0 ; dx = relu(net0)@w1+b1 ; out = x@wsc + dx
__global__ __launch_bounds__(128) void k_block0(
    const float* __restrict__ pts, const float* __restrict__ Wp, const float* __restrict__ bp,
    const float* __restrict__ w0, const float* __restrict__ b0,
    const float* __restrict__ w1, const float* __restrict__ b1,
    const float* __restrict__ wsc, float* __restrict__ net)
{
    const int P = 8;
    __shared__ float xs[P][256];
    __shared__ float h2[P][128];
    int j = threadIdx.x;
    int base = blockIdx.x * P;

    float bpj0 = bp[j], bpj1 = bp[j + 128];
    float wp00 = Wp[j],       wp01 = Wp[256 + j],  wp02 = Wp[512 + j];
    float wp10 = Wp[128 + j], wp11 = Wp[384 + j],  wp12 = Wp[640 + j];
#pragma unroll
    for (int p = 0; p < P; ++p) {
        int t = base + p;
        float px = pts[t * 3 + 0], py = pts[t * 3 + 1], pz = pts[t * 3 + 2];
        xs[p][j]       = fmaf(pz, wp02, fmaf(py, wp01, fmaf(px, wp00, bpj0)));
        xs[p][j + 128] = fmaf(pz, wp12, fmaf(py, wp11, fmaf(px, wp10, bpj1)));
    }
    __syncthreads();

    float acc[P], accS[P];
#pragma unroll
    for (int p = 0; p < P; ++p) { acc[p] = b0[j]; accS[p] = 0.f; }

    for (int k = 0; k < 256; k += 4) {
        float w0k[4], wsk[4];
#pragma unroll
        for (int q = 0; q < 4; ++q) { w0k[q] = w0[(k + q) * 128 + j]; wsk[q] = wsc[(k + q) * 128 + j]; }
#pragma unroll
        for (int p = 0; p < P; ++p) {
            float4 xv = *(const float4*)&xs[p][k];
            float xr[4] = {xv.x, xv.y, xv.z, xv.w};
#pragma unroll
            for (int q = 0; q < 4; ++q) {
                acc[p]  = fmaf(fmaxf(xr[q], 0.f), w0k[q], acc[p]);
                accS[p] = fmaf(xr[q], wsk[q], accS[p]);
            }
        }
    }
#pragma unroll
    for (int p = 0; p < P; ++p) h2[p][j] = fmaxf(acc[p], 0.f);
    __syncthreads();

#pragma unroll
    for (int p = 0; p < P; ++p) acc[p] = b1[j];
    for (int k = 0; k < 128; k += 4) {
        float w1k[4];
#pragma unroll
        for (int q = 0; q < 4; ++q) w1k[q] = w1[(k + q) * 128 + j];
#pragma unroll
        for (int p = 0; p < P; ++p) {
            float4 hv = *(const float4*)&h2[p][k];
            float hr[4] = {hv.x, hv.y, hv.z, hv.w};
#pragma unroll
            for (int q = 0; q < 4; ++q) acc[p] = fmaf(hr[q], w1k[q], acc[p]);
        }
    }
#pragma unroll
    for (int p = 0; p < P; ++p) net[(base + p) * HID + j] = accS[p] + acc[p];
}

// ---------- scatter max into 3 planes ----------
__global__ __launch_bounds__(256) void k_segmax(
    const float* __restrict__ net, const int* __restrict__ i0,
    const int* __restrict__ i1, const int* __restrict__ i2,
    float* __restrict__ seg)
{
    int b = blockIdx.y;
    int lin = blockIdx.x * 256 + threadIdx.x;   // over TPTS*128
    int c = lin & 127;
    int tt = lin >> 7;
    int t = b * TPTS + tt;
    float v = net[t * HID + c];
    int a0 = i0[t], a1 = i1[t], a2 = i2[t];
    atomicMaxF(&seg[((0 * BATCH + b) * R2 + a0) * HID + c], v);
    atomicMaxF(&seg[((1 * BATCH + b) * R2 + a1) * HID + c], v);
    atomicMaxF(&seg[((2 * BATCH + b) * R2 + a2) * HID + c], v);
}

// ---------- resnet block rounds 1..4 (gather fused) ----------
__global__ __launch_bounds__(128) void k_block(
    const float* __restrict__ net_in, const float* __restrict__ seg,
    const int* __restrict__ i0, const int* __restrict__ i1, const int* __restrict__ i2,
    const float* __restrict__ w0, const float* __restrict__ b0,
    const float* __restrict__ w1, const float* __restrict__ b1,
    const float* __restrict__ wsc, float* __restrict__ net_out)
{
    const int P = 8;
    __shared__ float xs[P][256];
    __shared__ float h2[P][128];
    int j = threadIdx.x;
    int b = blockIdx.y;
    int t0 = b * TPTS + blockIdx.x * P;
    const float* segb0 = seg + (0 * BATCH + b) * R2 * HID;
    const float* segb1 = seg + (1 * BATCH + b) * R2 * HID;
    const float* segb2 = seg + (2 * BATCH + b) * R2 * HID;

#pragma unroll
    for (int p = 0; p < P; ++p) {
        int t = t0 + p;
        xs[p][j] = net_in[t * HID + j];
        int a0 = i0[t], a1 = i1[t], a2 = i2[t];
        xs[p][128 + j] = segb0[a0 * HID + j] + segb1[a1 * HID + j] + segb2[a2 * HID + j];
    }
    __syncthreads();

    float acc[P], accS[P];
#pragma unroll
    for (int p = 0; p < P; ++p) { acc[p] = b0[j]; accS[p] = 0.f; }

    for (int k = 0; k < 256; k += 4) {
        float w0k[4], wsk[4];
#pragma unroll
        for (int q = 0; q < 4; ++q) { w0k[q] = w0[(k + q) * 128 + j]; wsk[q] = wsc[(k + q) * 128 + j]; }
#pragma unroll
        for (int p = 0; p < P; ++p) {
            float4 xv = *(const float4*)&xs[p][k];
            float xr[4] = {xv.x, xv.y, xv.z, xv.w};
#pragma unroll
            for (int q = 0; q < 4; ++q) {
                acc[p]  = fmaf(fmaxf(xr[q], 0.f), w0k[q], acc[p]);
                accS[p] = fmaf(xr[q], wsk[q], accS[p]);
            }
        }
    }
#pragma unroll
    for (int p = 0; p < P; ++p) h2[p][j] = fmaxf(acc[p], 0.f);
    __syncthreads();

#pragma unroll
    for (int p = 0; p < P; ++p) acc[p] = b1[j];
    for (int k = 0; k < 128; k += 4) {
        float w1k[4];
#pragma unroll
        for (int q = 0; q < 4; ++q) w1k[q] = w1[(k + q) * 128 + j];
#pragma unroll
        for (int p = 0; p < P; ++p) {
            float4 hv = *(const float4*)&h2[p][k];
            float hr[4] = {hv.x, hv.y, hv.z, hv.w};
#pragma unroll
            for (int q = 0; q < 4; ++q) acc[p] = fmaf(hr[q], w1k[q], acc[p]);
        }
    }
#pragma unroll
    for (int p = 0; p < P; ++p) net_out[(t0 + p) * HID + j] = accS[p] + acc[p];
}

// ---------- final: c = net @ Wc + bc, scatter-add into [bin][ch] accum + counts ----------
__global__ __launch_bounds__(128) void k_final(
    const float* __restrict__ net, const float* __restrict__ Wc, const float* __restrict__ bc,
    const int* __restrict__ i0, const int* __restrict__ i1, const int* __restrict__ i2,
    float* __restrict__ accp, float* __restrict__ cnt)
{
    const int P = 8;
    __shared__ float ns[P][128];
    int j = threadIdx.x;
    int b = blockIdx.y;
    int t0 = b * TPTS + blockIdx.x * P;
#pragma unroll
    for (int p = 0; p < P; ++p) ns[p][j] = net[(t0 + p) * HID + j];
    __syncthreads();

    float acc[P];
#pragma unroll
    for (int p = 0; p < P; ++p) acc[p] = bc[j];
    for (int k = 0; k < 128; k += 4) {
        float wk[4];
#pragma unroll
        for (int q = 0; q < 4; ++q) wk[q] = Wc[(k + q) * 128 + j];
#pragma unroll
        for (int p = 0; p < P; ++p) {
            float4 nv = *(const float4*)&ns[p][k];
            float nr[4] = {nv.x, nv.y, nv.z, nv.w};
#pragma unroll
            for (int q = 0; q < 4; ++q) acc[p] = fmaf(nr[q], wk[q], acc[p]);
        }
    }
#pragma unroll
    for (int p = 0; p < P; ++p) {
        int t = t0 + p;
        int a0 = i0[t], a1 = i1[t], a2 = i2[t];
        atomicAdd(&accp[((0 * BATCH + b) * R2 + a0) * HID + j], acc[p]);
        atomicAdd(&accp[((1 * BATCH + b) * R2 + a1) * HID + j], acc[p]);
        atomicAdd(&accp[((2 * BATCH + b) * R2 + a2) * HID + j], acc[p]);
        if (j == 0) {
            atomicAdd(&cnt[(0 * BATCH + b) * R2 + a0], 1.f);
            atomicAdd(&cnt[(1 * BATCH + b) * R2 + a1], 1.f);
            atomicAdd(&cnt[(2 * BATCH + b) * R2 + a2], 1.f);
        }
    }
}

// ---------- normalize + transpose [pb][bin][ch] -> out [pb][ch][bin] ----------
__global__ __launch_bounds__(256) void k_norm(
    const float* __restrict__ accp, const float* __restrict__ cnt, float* __restrict__ out)
{
    int i = blockIdx.x * 256 + threadIdx.x;   // over 3*B*128*4096 = 12,582,912
    int pb  = i >> 19;          // /(128*4096)
    int ch  = (i >> 12) & 127;
    int bin = i & 4095;
    float c = cnt[pb * R2 + bin];
    out[i] = accp[(pb * R2 + bin) * HID + ch] / fmaxf(c, 1.f);
}

extern "C" void kernel_launch(void* const* d_in, const int* in_sizes, int n_in,
                              void* d_out, int out_size, void* d_ws, size_t ws_size,
                              hipStream_t stream) {
    const float* pts  = (const float*)d_in[0];
    const int*   ixz  = (const int*)d_in[1];
    const int*   ixy  = (const int*)d_in[2];
    const int*   iyz  = (const int*)d_in[3];
    const float* Wp   = (const float*)d_in[4];
    const float* bp   = (const float*)d_in[5];
    const float* fc0w = (const float*)d_in[6];
    const float* fc0b = (const float*)d_in[7];
    const float* fc1w = (const float*)d_in[8];
    const float* fc1b = (const float*)d_in[9];
    const float* scw  = (const float*)d_in[10];
    const float* Wc   = (const float*)d_in[11];
    const float* bc   = (const float*)d_in[12];
    float* out = (float*)d_out;

    float* ws  = (float*)d_ws;
    float* net = ws;                      // 30,720,000 floats (122.9 MB)
    float* seg = ws + 30720000;           // 12,582,912 floats (50.3 MB) — reused as accp
    float* cnt = seg + 12582912;          // 98,304 floats

    const int SEGN = 3 * BATCH * R2 * HID;   // 12,582,912

    // block 0 (fused fc_pos)
    k_block0<<<dim3(NPTS / 8), 128, 0, stream>>>(pts, Wp, bp, fc0w, fc0b, fc1w, fc1b, scw, net);

    // rounds 1..4: scatter-max pool + resnet block (gather fused, net in-place)
    for (int r = 1; r < 5; ++r) {
        k_fill4<<<dim3(SEGN / 4 / 256), 256, 0, stream>>>((float4*)seg, -FLT_MAX, SEGN / 4);
        k_segmax<<<dim3(TPTS * 128 / 256, BATCH), 256, 0, stream>>>(net, ixz, ixy, iyz, seg);
        k_block<<<dim3(TPTS / 8, BATCH), 128, 0, stream>>>(
            net, seg, ixz, ixy, iyz,
            fc0w + r * 256 * 128, fc0b + r * 128,
            fc1w + r * 128 * 128, fc1b + r * 128,
            scw + r * 256 * 128, net);
    }

    // final projection + scatter-mean
    k_fill4<<<dim3(SEGN / 4 / 256), 256, 0, stream>>>((float4*)seg, 0.f, SEGN / 4);
    k_fill4<<<dim3(3 * BATCH * R2 / 4 / 256), 256, 0, stream>>>((float4*)cnt, 0.f, 3 * BATCH * R2 / 4);
    k_final<<<dim3(TPTS / 8, BATCH), 128, 0, stream>>>(net, Wc, bc, ixz, ixy, iyz, seg, cnt);
    k_norm<<<dim3(12582912 / 256), 256, 0, stream>>>(seg, cnt, out);
}

// Round 2
// 3213.460 us; speedup vs baseline: 2.1210x; 2.1210x over previous
//
#include <hip/hip_runtime.h>
#include <float.h>

#define BATCH 8
#define TPTS 30000
#define HID 128
#define R2 4096
#define NPTS (BATCH * TPTS)   // 240000
#define PB 64                 // points per block
#define XS 264                // xs row stride in bf16 elems (256 + 8 pad)
#define HS 136                // h row stride (128 + 8 pad)

typedef __attribute__((ext_vector_type(8))) short short8;
typedef __attribute__((ext_vector_type(4))) short short4v;
typedef __attribute__((ext_vector_type(4))) float f32x4;

__device__ __forceinline__ short f2bf(float f) {
    unsigned u = __float_as_uint(f);
    u += 0x7fff + ((u >> 16) & 1);   // RNE
    return (short)(u >> 16);
}

__device__ inline void atomicMaxF(float* addr, float v) {
    if (v >= 0.f) atomicMax((int*)addr, __float_as_int(v));
    else          atomicMin((unsigned int*)addr, __float_as_uint(v));
}

__global__ void k_fill4(float4* p, float v, int n4) {
    int i = blockIdx.x * blockDim.x + threadIdx.x;
    if (i < n4) p[i] = make_float4(v, v, v, v);
}

// ---------- weight prep: f32 [k][ch] -> bf16 transposed [ch][k] ----------
__global__ __launch_bounds__(256) void k_prep(
    const float* __restrict__ fc0w, const float* __restrict__ fc1w, const float* __restrict__ scw,
    short* __restrict__ Wt0, short* __restrict__ Wts, short* __restrict__ Wt1)
{
    int i = blockIdx.x * 256 + threadIdx.x;
    if (i < 5 * 128 * 256) {          // 163840
        int r = i >> 15;              // /32768
        int c = (i >> 8) & 127;
        int k = i & 255;
        Wt0[i] = f2bf(fc0w[(r * 256 + k) * 128 + c]);
        Wts[i] = f2bf(scw [(r * 256 + k) * 128 + c]);
    }
    if (i < 5 * 128 * 128) {          // 81920
        int r = i >> 14;
        int c = (i >> 7) & 127;
        int k = i & 127;
        Wt1[i] = f2bf(fc1w[(r * 128 + k) * 128 + c]);
    }
}

// ---------- shared LDS layout ----------
struct __align__(16) Lds {
    short xs_raw[PB * XS];    // raw x (shortcut input); reused as h after phase 1
    short xs_relu[PB * XS];   // relu(x) (fc0 input)
    float b0s[HID];
    float b1s[HID];
};

// ---------- MFMA resnet body (phases: fc0+sc, h-write, fc1, store) ----------
__device__ __forceinline__ void mfma_body(
    Lds& L, const short* __restrict__ Wt0r, const short* __restrict__ Wtsr,
    const short* __restrict__ Wt1r, float* __restrict__ net_out, int t0)
{
    int lane = threadIdx.x & 63;
    int wave = threadIdx.x >> 6;
    int n    = lane & 15;       // pt within 16-tile / A-row select
    int quad = lane >> 4;       // k-group / C-row group
    int ch0  = wave * 32;

    f32x4 accF[2][4] = {};      // fc0 pre-activation
    f32x4 accS[2][4] = {};      // shortcut, later += fc1

    // phase 1: net0 = relu(x)@w0 ; sc = x@wsc   (K = 256)
    for (int ks = 0; ks < 8; ++ks) {
        int ko = ks * 32 + quad * 8;
        short8 aF[2], aS[2];
#pragma unroll
        for (int c = 0; c < 2; ++c) {
            int row = ch0 + c * 16 + n;
            aF[c] = *(const short8*)(Wt0r + row * 256 + ko);
            aS[c] = *(const short8*)(Wtsr + row * 256 + ko);
        }
#pragma unroll
        for (int p = 0; p < 4; ++p) {
            int prow = (p * 16 + n) * XS + ko;
            short8 bR = *(const short8*)(L.xs_relu + prow);
            short8 bX = *(const short8*)(L.xs_raw  + prow);
#pragma unroll
            for (int c = 0; c < 2; ++c) {
                accF[c][p] = __builtin_amdgcn_mfma_f32_16x16x32_bf16(aF[c], bR, accF[c][p], 0, 0, 0);
                accS[c][p] = __builtin_amdgcn_mfma_f32_16x16x32_bf16(aS[c], bX, accS[c][p], 0, 0, 0);
            }
        }
    }
    __syncthreads();            // xs_raw reads done; safe to alias h

    // h = relu(net0 + b0) -> LDS [pt][ch] bf16
    short* h = L.xs_raw;
#pragma unroll
    for (int c = 0; c < 2; ++c) {
        int chb = ch0 + c * 16 + quad * 4;
#pragma unroll
        for (int p = 0; p < 4; ++p) {
            int pt = p * 16 + n;
            short4v hv;
#pragma unroll
            for (int r = 0; r < 4; ++r)
                hv[r] = f2bf(fmaxf(accF[c][p][r] + L.b0s[chb + r], 0.f));
            *(short4v*)&h[pt * HS + chb] = hv;
        }
    }
    __syncthreads();

    // phase 2: accS += h @ w1   (K = 128)
    for (int ks = 0; ks < 4; ++ks) {
        int ko = ks * 32 + quad * 8;
        short8 a1[2];
#pragma unroll
        for (int c = 0; c < 2; ++c)
            a1[c] = *(const short8*)(Wt1r + (ch0 + c * 16 + n) * 128 + ko);
#pragma unroll
        for (int p = 0; p < 4; ++p) {
            short8 bh = *(const short8*)&h[(p * 16 + n) * HS + ko];
#pragma unroll
            for (int c = 0; c < 2; ++c)
                accS[c][p] = __builtin_amdgcn_mfma_f32_16x16x32_bf16(a1[c], bh, accS[c][p], 0, 0, 0);
        }
    }

    // store: net_out[pt][ch] = sc + dx + b1
#pragma unroll
    for (int c = 0; c < 2; ++c) {
        int chb = ch0 + c * 16 + quad * 4;
#pragma unroll
        for (int p = 0; p < 4; ++p) {
            int pt = p * 16 + n;
            f32x4 o;
#pragma unroll
            for (int r = 0; r < 4; ++r)
                o[r] = accS[c][p][r] + L.b1s[chb + r];
            *(f32x4*)&net_out[(t0 + pt) * HID + chb] = o;
        }
    }
}

// ---------- block 0: stage x = pts@Wp+bp, then resnet ----------
__global__ __launch_bounds__(256) void k_mblock0(
    const float* __restrict__ pts, const float* __restrict__ Wp, const float* __restrict__ bp,
    const short* __restrict__ Wt0, const short* __restrict__ Wts, const short* __restrict__ Wt1,
    const float* __restrict__ b0, const float* __restrict__ b1, float* __restrict__ net)
{
    __shared__ Lds L;
    int tid = threadIdx.x;
    int t0 = blockIdx.x * PB;
    if (tid < 128) { L.b0s[tid] = b0[tid]; L.b1s[tid] = b1[tid]; }

    int j = tid & 127, half = tid >> 7;
    int col = half * 128 + j;
    float w0 = Wp[col], w1 = Wp[256 + col], w2 = Wp[512 + col];
    float bb = bp[col];
    for (int p = 0; p < PB; ++p) {
        int t = t0 + p;
        float px = pts[t * 3], py = pts[t * 3 + 1], pz = pts[t * 3 + 2];
        float v = fmaf(pz, w2, fmaf(py, w1, fmaf(px, w0, bb)));
        L.xs_raw[p * XS + col]  = f2bf(v);
        L.xs_relu[p * XS + col] = f2bf(fmaxf(v, 0.f));
    }
    __syncthreads();
    mfma_body(L, Wt0, Wts, Wt1, net, t0);
}

// ---------- blocks 1..4: stage x = [net | pooled], then resnet ----------
__global__ __launch_bounds__(256) void k_mblock(
    const float* __restrict__ net_in, const float* __restrict__ seg,
    const int* __restrict__ i0, const int* __restrict__ i1, const int* __restrict__ i2,
    const short* __restrict__ Wt0, const short* __restrict__ Wts, const short* __restrict__ Wt1,
    const float* __restrict__ b0, const float* __restrict__ b1, float* __restrict__ net_out)
{
    __shared__ Lds L;
    int tid = threadIdx.x;
    int t0 = blockIdx.x * PB;
    if (tid < 128) { L.b0s[tid] = b0[tid]; L.b1s[tid] = b1[tid]; }

    int j = tid & 127;
    for (int p = tid >> 7; p < PB; p += 2) {
        int t = t0 + p;
        int bb = t / TPTS;
        float nv = net_in[t * HID + j];
        int a0 = i0[t], a1 = i1[t], a2 = i2[t];
        float pv = seg[((0 * BATCH + bb) * R2 + a0) * HID + j]
                 + seg[((1 * BATCH + bb) * R2 + a1) * HID + j]
                 + seg[((2 * BATCH + bb) * R2 + a2) * HID + j];
        L.xs_raw[p * XS + j]        = f2bf(nv);
        L.xs_raw[p * XS + 128 + j]  = f2bf(pv);
        L.xs_relu[p * XS + j]       = f2bf(fmaxf(nv, 0.f));
        L.xs_relu[p * XS + 128 + j] = f2bf(fmaxf(pv, 0.f));
    }
    __syncthreads();
    mfma_body(L, Wt0, Wts, Wt1, net_out, t0);
}

// ---------- scatter max into 3 planes ----------
__global__ __launch_bounds__(256) void k_segmax(
    const float* __restrict__ net, const int* __restrict__ i0,
    const int* __restrict__ i1, const int* __restrict__ i2,
    float* __restrict__ seg)
{
    int b = blockIdx.y;
    int lin = blockIdx.x * 256 + threadIdx.x;
    int c = lin & 127;
    int tt = lin >> 7;
    int t = b * TPTS + tt;
    float v = net[t * HID + c];
    int a0 = i0[t], a1 = i1[t], a2 = i2[t];
    atomicMaxF(&seg[((0 * BATCH + b) * R2 + a0) * HID + c], v);
    atomicMaxF(&seg[((1 * BATCH + b) * R2 + a1) * HID + c], v);
    atomicMaxF(&seg[((2 * BATCH + b) * R2 + a2) * HID + c], v);
}

// ---------- final: c = net @ Wc + bc, scatter-add ----------
__global__ __launch_bounds__(128) void k_final(
    const float* __restrict__ net, const float* __restrict__ Wc, const float* __restrict__ bc,
    const int* __restrict__ i0, const int* __restrict__ i1, const int* __restrict__ i2,
    float* __restrict__ accp, float* __restrict__ cnt)
{
    const int P = 8;
    __shared__ float ns[P][128];
    int j = threadIdx.x;
    int b = blockIdx.y;
    int t0 = b * TPTS + blockIdx.x * P;
#pragma unroll
    for (int p = 0; p < P; ++p) ns[p][j] = net[(t0 + p) * HID + j];
    __syncthreads();

    float acc[P];
#pragma unroll
    for (int p = 0; p < P; ++p) acc[p] = bc[j];
    for (int k = 0; k < 128; k += 4) {
        float wk[4];
#pragma unroll
        for (int q = 0; q < 4; ++q) wk[q] = Wc[(k + q) * 128 + j];
#pragma unroll
        for (int p = 0; p < P; ++p) {
            float4 nv = *(const float4*)&ns[p][k];
            float nr[4] = {nv.x, nv.y, nv.z, nv.w};
#pragma unroll
            for (int q = 0; q < 4; ++q) acc[p] = fmaf(nr[q], wk[q], acc[p]);
        }
    }
#pragma unroll
    for (int p = 0; p < P; ++p) {
        int t = t0 + p;
        int a0 = i0[t], a1 = i1[t], a2 = i2[t];
        atomicAdd(&accp[((0 * BATCH + b) * R2 + a0) * HID + j], acc[p]);
        atomicAdd(&accp[((1 * BATCH + b) * R2 + a1) * HID + j], acc[p]);
        atomicAdd(&accp[((2 * BATCH + b) * R2 + a2) * HID + j], acc[p]);
        if (j == 0) {
            atomicAdd(&cnt[(0 * BATCH + b) * R2 + a0], 1.f);
            atomicAdd(&cnt[(1 * BATCH + b) * R2 + a1], 1.f);
            atomicAdd(&cnt[(2 * BATCH + b) * R2 + a2], 1.f);
        }
    }
}

// ---------- normalize + transpose ----------
__global__ __launch_bounds__(256) void k_norm(
    const float* __restrict__ accp, const float* __restrict__ cnt, float* __restrict__ out)
{
    int i = blockIdx.x * 256 + threadIdx.x;
    int pb  = i >> 19;
    int ch  = (i >> 12) & 127;
    int bin = i & 4095;
    float c = cnt[pb * R2 + bin];
    out[i] = accp[(pb * R2 + bin) * HID + ch] / fmaxf(c, 1.f);
}

extern "C" void kernel_launch(void* const* d_in, const int* in_sizes, int n_in,
                              void* d_out, int out_size, void* d_ws, size_t ws_size,
                              hipStream_t stream) {
    const float* pts  = (const float*)d_in[0];
    const int*   ixz  = (const int*)d_in[1];
    const int*   ixy  = (const int*)d_in[2];
    const int*   iyz  = (const int*)d_in[3];
    const float* Wp   = (const float*)d_in[4];
    const float* bp   = (const float*)d_in[5];
    const float* fc0w = (const float*)d_in[6];
    const float* fc0b = (const float*)d_in[7];
    const float* fc1w = (const float*)d_in[8];
    const float* fc1b = (const float*)d_in[9];
    const float* scw  = (const float*)d_in[10];
    const float* Wc   = (const float*)d_in[11];
    const float* bc   = (const float*)d_in[12];
    float* out = (float*)d_out;

    // ws layout: bf16 weights first, then net / seg / cnt
    short* Wt0 = (short*)d_ws;            // 163840 shorts
    short* Wts = Wt0 + 163840;            // 163840
    short* Wt1 = Wts + 163840;            // 81920
    float* net = (float*)(Wt1 + 81920);   // 30,720,000 floats
    float* seg = net + 30720000;          // 12,582,912 floats (accp reuse)
    float* cnt = seg + 12582912;          // 98,304 floats

    const int SEGN = 3 * BATCH * R2 * HID;

    k_prep<<<dim3(640), 256, 0, stream>>>(fc0w, fc1w, scw, Wt0, Wts, Wt1);

    k_mblock0<<<dim3(NPTS / PB), 256, 0, stream>>>(pts, Wp, bp, Wt0, Wts, Wt1, fc0b, fc1b, net);

    for (int r = 1; r < 5; ++r) {
        k_fill4<<<dim3(SEGN / 4 / 256), 256, 0, stream>>>((float4*)seg, -FLT_MAX, SEGN / 4);
        k_segmax<<<dim3(TPTS * 128 / 256, BATCH), 256, 0, stream>>>(net, ixz, ixy, iyz, seg);
        k_mblock<<<dim3(NPTS / PB), 256, 0, stream>>>(
            net, seg, ixz, ixy, iyz,
            Wt0 + r * 32768, Wts + r * 32768, Wt1 + r * 16384,
            fc0b + r * 128, fc1b + r * 128, net);
    }

    k_fill4<<<dim3(SEGN / 4 / 256), 256, 0, stream>>>((float4*)seg, 0.f, SEGN / 4);
    k_fill4<<<dim3(3 * BATCH * R2 / 4 / 256), 256, 0, stream>>>((float4*)cnt, 0.f, 3 * BATCH * R2 / 4);
    k_final<<<dim3(TPTS / 8, BATCH), 128, 0, stream>>>(net, Wc, bc, ixz, ixy, iyz, seg, cnt);
    k_norm<<<dim3(12582912 / 256), 256, 0, stream>>>(seg, cnt, out);
}

// Round 3
// 1519.510 us; speedup vs baseline: 4.4855x; 2.1148x over previous
//
#include <hip/hip_runtime.h>
#include <float.h>

#define BATCH 8
#define TPTS 30000
#define HID 128
#define R2 4096
#define NPTS (BATCH * TPTS)   // 240000
#define PB 64                 // points per block
#define XS 264                // xs row stride in bf16 elems (256 + 8 pad)
#define HS 136                // h row stride (128 + 8 pad)

typedef __attribute__((ext_vector_type(8))) short short8;
typedef __attribute__((ext_vector_type(4))) short short4v;
typedef __attribute__((ext_vector_type(4))) float f32x4;

__device__ __forceinline__ short f2bf(float f) {
    unsigned u = __float_as_uint(f);
    u += 0x7fff + ((u >> 16) & 1);   // RNE
    return (short)(u >> 16);
}

__global__ void k_fill4(float4* p, float v, int n4) {
    int i = blockIdx.x * blockDim.x + threadIdx.x;
    if (i < n4) p[i] = make_float4(v, v, v, v);
}

// ---------- weight prep: f32 [k][ch] -> bf16 transposed [ch][k] ----------
__global__ __launch_bounds__(256) void k_prep(
    const float* __restrict__ fc0w, const float* __restrict__ fc1w, const float* __restrict__ scw,
    const float* __restrict__ fccw,
    short* __restrict__ Wt0, short* __restrict__ Wts, short* __restrict__ Wt1,
    short* __restrict__ Wtc)
{
    int i = blockIdx.x * 256 + threadIdx.x;
    if (i < 5 * 128 * 256) {          // 163840
        int r = i >> 15;
        int c = (i >> 8) & 127;
        int k = i & 255;
        Wt0[i] = f2bf(fc0w[(r * 256 + k) * 128 + c]);
        Wts[i] = f2bf(scw [(r * 256 + k) * 128 + c]);
    }
    if (i < 5 * 128 * 128) {          // 81920
        int r = i >> 14;
        int c = (i >> 7) & 127;
        int k = i & 127;
        Wt1[i] = f2bf(fc1w[(r * 128 + k) * 128 + c]);
    }
    if (i < 128 * 128) {              // 16384
        int c = (i >> 7) & 127;
        int k = i & 127;
        Wtc[i] = f2bf(fccw[k * 128 + c]);
    }
}

// ---------- counting sort of points by bin (per plane, per batch) ----------
__global__ void k_hist(const int* __restrict__ i0, const int* __restrict__ i1,
                       const int* __restrict__ i2, int* __restrict__ hist)
{
    int t = blockIdx.x * 256 + threadIdx.x;
    if (t >= NPTS) return;
    int b = t / TPTS;
    atomicAdd(&hist[(0 * BATCH + b) * R2 + i0[t]], 1);
    atomicAdd(&hist[(1 * BATCH + b) * R2 + i1[t]], 1);
    atomicAdd(&hist[(2 * BATCH + b) * R2 + i2[t]], 1);
}

__global__ __launch_bounds__(256) void k_scan(const int* __restrict__ hist,
                                              int* __restrict__ starts, int* __restrict__ cursor)
{
    int pb = blockIdx.x;                 // 0..23
    const int* h = hist + pb * R2;
    int tid = threadIdx.x;
    __shared__ int part[257];
    int loc[16]; int s = 0;
    int base = tid * 16;
#pragma unroll
    for (int q = 0; q < 16; ++q) { loc[q] = s; s += h[base + q]; }
    part[tid + 1] = s;
    __syncthreads();
    if (tid == 0) {
        part[0] = 0;
        for (int i = 1; i <= 256; ++i) part[i] += part[i - 1];
    }
    __syncthreads();
    int off = part[tid];
#pragma unroll
    for (int q = 0; q < 16; ++q) {
        int v = off + loc[q];
        starts[pb * 4097 + base + q] = v;
        cursor[pb * R2 + base + q] = v;
    }
    if (tid == 255) starts[pb * 4097 + 4096] = part[256];
}

__global__ void k_scatter(const int* __restrict__ i0, const int* __restrict__ i1,
                          const int* __restrict__ i2, int* __restrict__ cursor,
                          unsigned short* __restrict__ order)
{
    int t = blockIdx.x * 256 + threadIdx.x;
    if (t >= NPTS) return;
    int b = t / TPTS;
    int tt = t - b * TPTS;
    int s0 = atomicAdd(&cursor[(0 * BATCH + b) * R2 + i0[t]], 1);
    order[(0 * BATCH + b) * TPTS + s0] = (unsigned short)tt;
    int s1 = atomicAdd(&cursor[(1 * BATCH + b) * R2 + i1[t]], 1);
    order[(1 * BATCH + b) * TPTS + s1] = (unsigned short)tt;
    int s2 = atomicAdd(&cursor[(2 * BATCH + b) * R2 + i2[t]], 1);
    order[(2 * BATCH + b) * TPTS + s2] = (unsigned short)tt;
}

// ---------- gather-based pool max: one wave per bin ----------
__global__ __launch_bounds__(256) void k_poolmax(
    const float* __restrict__ net, const int* __restrict__ starts,
    const unsigned short* __restrict__ order, float* __restrict__ seg)
{
    int pb = blockIdx.y;
    int bin = blockIdx.x * 4 + (threadIdx.x >> 6);
    int lane = threadIdx.x & 63;
    int s = starts[pb * 4097 + bin], e = starts[pb * 4097 + bin + 1];
    if (s == e) return;                       // empty bins never gathered
    int b = pb & 7;
    const unsigned short* ord = order + pb * TPTS;
    float2 v = make_float2(-FLT_MAX, -FLT_MAX);
    for (int i = s; i < e; ++i) {
        int t = b * TPTS + ord[i];
        float2 x = *(const float2*)&net[t * HID + lane * 2];
        v.x = fmaxf(v.x, x.x); v.y = fmaxf(v.y, x.y);
    }
    *(float2*)&seg[(pb * R2 + bin) * HID + lane * 2] = v;
}

// ---------- gather-based pool mean (final): divide by count, write [pb][bin][ch] ----------
__global__ __launch_bounds__(256) void k_poolmean(
    const float* __restrict__ cfeat, const int* __restrict__ starts,
    const unsigned short* __restrict__ order, float* __restrict__ seg)
{
    int pb = blockIdx.y;
    int bin = blockIdx.x * 4 + (threadIdx.x >> 6);
    int lane = threadIdx.x & 63;
    int s = starts[pb * 4097 + bin], e = starts[pb * 4097 + bin + 1];
    int b = pb & 7;
    const unsigned short* ord = order + pb * TPTS;
    float2 v = make_float2(0.f, 0.f);
    for (int i = s; i < e; ++i) {
        int t = b * TPTS + ord[i];
        float2 x = *(const float2*)&cfeat[t * HID + lane * 2];
        v.x += x.x; v.y += x.y;
    }
    float inv = 1.f / fmaxf((float)(e - s), 1.f);
    v.x *= inv; v.y *= inv;
    *(float2*)&seg[(pb * R2 + bin) * HID + lane * 2] = v;   // empty bins -> 0
}

// ---------- shared LDS layout for resnet ----------
struct __align__(16) Lds {
    short xs_raw[PB * XS];
    short xs_relu[PB * XS];
    float b0s[HID];
    float b1s[HID];
};

__device__ __forceinline__ void mfma_body(
    Lds& L, const short* __restrict__ Wt0r, const short* __restrict__ Wtsr,
    const short* __restrict__ Wt1r, float* __restrict__ net_out, int t0)
{
    int lane = threadIdx.x & 63;
    int wave = threadIdx.x >> 6;
    int n    = lane & 15;
    int quad = lane >> 4;
    int ch0  = wave * 32;

    f32x4 accF[2][4] = {};
    f32x4 accS[2][4] = {};

    for (int ks = 0; ks < 8; ++ks) {
        int ko = ks * 32 + quad * 8;
        short8 aF[2], aS[2];
#pragma unroll
        for (int c = 0; c < 2; ++c) {
            int row = ch0 + c * 16 + n;
            aF[c] = *(const short8*)(Wt0r + row * 256 + ko);
            aS[c] = *(const short8*)(Wtsr + row * 256 + ko);
        }
#pragma unroll
        for (int p = 0; p < 4; ++p) {
            int prow = (p * 16 + n) * XS + ko;
            short8 bR = *(const short8*)(L.xs_relu + prow);
            short8 bX = *(const short8*)(L.xs_raw  + prow);
#pragma unroll
            for (int c = 0; c < 2; ++c) {
                accF[c][p] = __builtin_amdgcn_mfma_f32_16x16x32_bf16(aF[c], bR, accF[c][p], 0, 0, 0);
                accS[c][p] = __builtin_amdgcn_mfma_f32_16x16x32_bf16(aS[c], bX, accS[c][p], 0, 0, 0);
            }
        }
    }
    __syncthreads();

    short* h = L.xs_raw;
#pragma unroll
    for (int c = 0; c < 2; ++c) {
        int chb = ch0 + c * 16 + quad * 4;
#pragma unroll
        for (int p = 0; p < 4; ++p) {
            int pt = p * 16 + n;
            short4v hv;
#pragma unroll
            for (int r = 0; r < 4; ++r)
                hv[r] = f2bf(fmaxf(accF[c][p][r] + L.b0s[chb + r], 0.f));
            *(short4v*)&h[pt * HS + chb] = hv;
        }
    }
    __syncthreads();

    for (int ks = 0; ks < 4; ++ks) {
        int ko = ks * 32 + quad * 8;
        short8 a1[2];
#pragma unroll
        for (int c = 0; c < 2; ++c)
            a1[c] = *(const short8*)(Wt1r + (ch0 + c * 16 + n) * 128 + ko);
#pragma unroll
        for (int p = 0; p < 4; ++p) {
            short8 bh = *(const short8*)&h[(p * 16 + n) * HS + ko];
#pragma unroll
            for (int c = 0; c < 2; ++c)
                accS[c][p] = __builtin_amdgcn_mfma_f32_16x16x32_bf16(a1[c], bh, accS[c][p], 0, 0, 0);
        }
    }

#pragma unroll
    for (int c = 0; c < 2; ++c) {
        int chb = ch0 + c * 16 + quad * 4;
#pragma unroll
        for (int p = 0; p < 4; ++p) {
            int pt = p * 16 + n;
            f32x4 o;
#pragma unroll
            for (int r = 0; r < 4; ++r)
                o[r] = accS[c][p][r] + L.b1s[chb + r];
            *(f32x4*)&net_out[(t0 + pt) * HID + chb] = o;
        }
    }
}

__global__ __launch_bounds__(256) void k_mblock0(
    const float* __restrict__ pts, const float* __restrict__ Wp, const float* __restrict__ bp,
    const short* __restrict__ Wt0, const short* __restrict__ Wts, const short* __restrict__ Wt1,
    const float* __restrict__ b0, const float* __restrict__ b1, float* __restrict__ net)
{
    __shared__ Lds L;
    int tid = threadIdx.x;
    int t0 = blockIdx.x * PB;
    if (tid < 128) { L.b0s[tid] = b0[tid]; L.b1s[tid] = b1[tid]; }

    int j = tid & 127, half = tid >> 7;
    int col = half * 128 + j;
    float w0 = Wp[col], w1 = Wp[256 + col], w2 = Wp[512 + col];
    float bb = bp[col];
    for (int p = 0; p < PB; ++p) {
        int t = t0 + p;
        float px = pts[t * 3], py = pts[t * 3 + 1], pz = pts[t * 3 + 2];
        float v = fmaf(pz, w2, fmaf(py, w1, fmaf(px, w0, bb)));
        L.xs_raw[p * XS + col]  = f2bf(v);
        L.xs_relu[p * XS + col] = f2bf(fmaxf(v, 0.f));
    }
    __syncthreads();
    mfma_body(L, Wt0, Wts, Wt1, net, t0);
}

__global__ __launch_bounds__(256) void k_mblock(
    const float* __restrict__ net_in, const float* __restrict__ seg,
    const int* __restrict__ i0, const int* __restrict__ i1, const int* __restrict__ i2,
    const short* __restrict__ Wt0, const short* __restrict__ Wts, const short* __restrict__ Wt1,
    const float* __restrict__ b0, const float* __restrict__ b1, float* __restrict__ net_out)
{
    __shared__ Lds L;
    int tid = threadIdx.x;
    int t0 = blockIdx.x * PB;
    if (tid < 128) { L.b0s[tid] = b0[tid]; L.b1s[tid] = b1[tid]; }

    int j = tid & 127;
    for (int p = tid >> 7; p < PB; p += 2) {
        int t = t0 + p;
        int bb = t / TPTS;
        float nv = net_in[t * HID + j];
        int a0 = i0[t], a1 = i1[t], a2 = i2[t];
        float pv = seg[((0 * BATCH + bb) * R2 + a0) * HID + j]
                 + seg[((1 * BATCH + bb) * R2 + a1) * HID + j]
                 + seg[((2 * BATCH + bb) * R2 + a2) * HID + j];
        L.xs_raw[p * XS + j]        = f2bf(nv);
        L.xs_raw[p * XS + 128 + j]  = f2bf(pv);
        L.xs_relu[p * XS + j]       = f2bf(fmaxf(nv, 0.f));
        L.xs_relu[p * XS + 128 + j] = f2bf(fmaxf(pv, 0.f));
    }
    __syncthreads();
    mfma_body(L, Wt0, Wts, Wt1, net_out, t0);
}

// ---------- final projection c = net@Wc + bc via MFMA, in-place ----------
__global__ __launch_bounds__(256) void k_finalm(
    float* __restrict__ net, const short* __restrict__ Wtc, const float* __restrict__ bc)
{
    __shared__ short hbuf[PB * HS];
    __shared__ float bcs[HID];
    int tid = threadIdx.x;
    int t0 = blockIdx.x * PB;
    if (tid < 128) bcs[tid] = bc[tid];
    int j = tid & 127;
    for (int p = tid >> 7; p < PB; p += 2)
        hbuf[p * HS + j] = f2bf(net[(t0 + p) * HID + j]);
    __syncthreads();

    int lane = tid & 63, wave = tid >> 6;
    int n = lane & 15, quad = lane >> 4;
    int ch0 = wave * 32;
    f32x4 acc[2][4] = {};
    for (int ks = 0; ks < 4; ++ks) {
        int ko = ks * 32 + quad * 8;
        short8 a[2];
#pragma unroll
        for (int c = 0; c < 2; ++c)
            a[c] = *(const short8*)(Wtc + (ch0 + c * 16 + n) * 128 + ko);
#pragma unroll
        for (int p = 0; p < 4; ++p) {
            short8 bh = *(const short8*)&hbuf[(p * 16 + n) * HS + ko];
#pragma unroll
            for (int c = 0; c < 2; ++c)
                acc[c][p] = __builtin_amdgcn_mfma_f32_16x16x32_bf16(a[c], bh, acc[c][p], 0, 0, 0);
        }
    }
#pragma unroll
    for (int c = 0; c < 2; ++c) {
        int chb = ch0 + c * 16 + quad * 4;
#pragma unroll
        for (int p = 0; p < 4; ++p) {
            int pt = p * 16 + n;
            f32x4 o;
#pragma unroll
            for (int r = 0; r < 4; ++r)
                o[r] = acc[c][p][r] + bcs[chb + r];
            *(f32x4*)&net[(t0 + pt) * HID + chb] = o;
        }
    }
}

// ---------- transpose [pb][bin][ch] -> out [pb][ch][bin] ----------
__global__ __launch_bounds__(256) void k_norm(
    const float* __restrict__ seg, float* __restrict__ out)
{
    int i = blockIdx.x * 256 + threadIdx.x;
    int pb  = i >> 19;
    int ch  = (i >> 12) & 127;
    int bin = i & 4095;
    out[i] = seg[(pb * R2 + bin) * HID + ch];
}

extern "C" void kernel_launch(void* const* d_in, const int* in_sizes, int n_in,
                              void* d_out, int out_size, void* d_ws, size_t ws_size,
                              hipStream_t stream) {
    const float* pts  = (const float*)d_in[0];
    const int*   ixz  = (const int*)d_in[1];
    const int*   ixy  = (const int*)d_in[2];
    const int*   iyz  = (const int*)d_in[3];
    const float* Wp   = (const float*)d_in[4];
    const float* bp   = (const float*)d_in[5];
    const float* fc0w = (const float*)d_in[6];
    const float* fc0b = (const float*)d_in[7];
    const float* fc1w = (const float*)d_in[8];
    const float* fc1b = (const float*)d_in[9];
    const float* scw  = (const float*)d_in[10];
    const float* Wc   = (const float*)d_in[11];
    const float* bc   = (const float*)d_in[12];
    float* out = (float*)d_out;

    short* Wt0 = (short*)d_ws;            // 163840
    short* Wts = Wt0 + 163840;            // 163840
    short* Wt1 = Wts + 163840;            // 81920
    short* Wtc = Wt1 + 81920;             // 16384  (total 425984 shorts, 16B-aligned)
    float* net = (float*)(Wtc + 16384);   // 30,720,000 floats
    float* seg = net + 30720000;          // 12,582,912 floats
    int* hist   = (int*)(seg + 12582912); // 98304 (doubles as cursor)
    int* starts = hist + 98304;           // 24*4097 = 98328
    unsigned short* order = (unsigned short*)(starts + 98328); // 720000

    // weight prep + counting sort of (plane,batch) points by bin — indices are static
    k_prep<<<dim3(640), 256, 0, stream>>>(fc0w, fc1w, scw, Wc, Wt0, Wts, Wt1, Wtc);
    k_fill4<<<dim3(96), 256, 0, stream>>>((float4*)hist, 0.f, 98304 / 4);
    k_hist<<<dim3((NPTS + 255) / 256), 256, 0, stream>>>(ixz, ixy, iyz, hist);
    k_scan<<<dim3(24), 256, 0, stream>>>(hist, starts, hist);
    k_scatter<<<dim3((NPTS + 255) / 256), 256, 0, stream>>>(ixz, ixy, iyz, hist, order);

    k_mblock0<<<dim3(NPTS / PB), 256, 0, stream>>>(pts, Wp, bp, Wt0, Wts, Wt1, fc0b, fc1b, net);

    for (int r = 1; r < 5; ++r) {
        k_poolmax<<<dim3(R2 / 4, 24), 256, 0, stream>>>(net, starts, order, seg);
        k_mblock<<<dim3(NPTS / PB), 256, 0, stream>>>(
            net, seg, ixz, ixy, iyz,
            Wt0 + r * 32768, Wts + r * 32768, Wt1 + r * 16384,
            fc0b + r * 128, fc1b + r * 128, net);
    }

    k_finalm<<<dim3(NPTS / PB), 256, 0, stream>>>(net, Wtc, bc);
    k_poolmean<<<dim3(R2 / 4, 24), 256, 0, stream>>>(net, starts, order, seg);
    k_norm<<<dim3(12582912 / 256), 256, 0, stream>>>(seg, out);
}

// Round 5
// 1312.116 us; speedup vs baseline: 5.1945x; 1.1581x over previous
//
#include <hip/hip_runtime.h>
#include <float.h>

#define BATCH 8
#define TPTS 30000
#define HID 128
#define R2 4096
#define NPTS (BATCH * TPTS)   // 240000
#define PB 64                 // points per block
#define XS 264                // xs row stride in bf16 elems (256 + 8 pad)
#define HS 136                // h row stride (128 + 8 pad)

typedef __attribute__((ext_vector_type(8))) short short8;
typedef __attribute__((ext_vector_type(4))) short short4v;
typedef __attribute__((ext_vector_type(4))) float f32x4;

__device__ __forceinline__ short f2bf(float f) {
    unsigned u = __float_as_uint(f);
    u += 0x7fff + ((u >> 16) & 1);   // RNE
    return (short)(u >> 16);
}
__device__ __forceinline__ float bf2f(unsigned short u) {
    return __uint_as_float(((unsigned)u) << 16);
}
// packed relu on two bf16 in one dword: negative -> sign-only (-0.0, harmless as matmul input)
__device__ __forceinline__ unsigned relu2(unsigned u) {
    unsigned sm = u & 0x80008000u;
    unsigned d  = sm - (sm >> 15);
    return u & ~d;
}

__global__ void k_fill4(float4* p, float v, int n4) {
    int i = blockIdx.x * blockDim.x + threadIdx.x;
    if (i < n4) p[i] = make_float4(v, v, v, v);
}

// ---------- weight prep: f32 [k][ch] -> bf16 transposed [ch][k] ----------
__global__ __launch_bounds__(256) void k_prep(
    const float* __restrict__ fc0w, const float* __restrict__ fc1w, const float* __restrict__ scw,
    const float* __restrict__ fccw,
    short* __restrict__ Wt0, short* __restrict__ Wts, short* __restrict__ Wt1,
    short* __restrict__ Wtc)
{
    int i = blockIdx.x * 256 + threadIdx.x;
    if (i < 5 * 128 * 256) {
        int r = i >> 15;
        int c = (i >> 8) & 127;
        int k = i & 255;
        Wt0[i] = f2bf(fc0w[(r * 256 + k) * 128 + c]);
        Wts[i] = f2bf(scw [(r * 256 + k) * 128 + c]);
    }
    if (i < 5 * 128 * 128) {
        int r = i >> 14;
        int c = (i >> 7) & 127;
        int k = i & 127;
        Wt1[i] = f2bf(fc1w[(r * 128 + k) * 128 + c]);
    }
    if (i < 128 * 128) {
        int c = (i >> 7) & 127;
        int k = i & 127;
        Wtc[i] = f2bf(fccw[k * 128 + c]);
    }
}

// ---------- counting sort of points by bin (per plane, per batch) ----------
__global__ void k_hist(const int* __restrict__ i0, const int* __restrict__ i1,
                       const int* __restrict__ i2, int* __restrict__ hist)
{
    int t = blockIdx.x * 256 + threadIdx.x;
    if (t >= NPTS) return;
    int b = t / TPTS;
    atomicAdd(&hist[(0 * BATCH + b) * R2 + i0[t]], 1);
    atomicAdd(&hist[(1 * BATCH + b) * R2 + i1[t]], 1);
    atomicAdd(&hist[(2 * BATCH + b) * R2 + i2[t]], 1);
}

__global__ __launch_bounds__(256) void k_scan(const int* __restrict__ hist,
                                              int* __restrict__ starts, int* __restrict__ cursor)
{
    int pb = blockIdx.x;                 // 0..23
    const int* h = hist + pb * R2;
    int tid = threadIdx.x;
    __shared__ int part[257];
    int loc[16]; int s = 0;
    int base = tid * 16;
#pragma unroll
    for (int q = 0; q < 16; ++q) { loc[q] = s; s += h[base + q]; }
    part[tid + 1] = s;
    __syncthreads();
    if (tid == 0) {
        part[0] = 0;
        for (int i = 1; i <= 256; ++i) part[i] += part[i - 1];
    }
    __syncthreads();
    int off = part[tid];
#pragma unroll
    for (int q = 0; q < 16; ++q) {
        int v = off + loc[q];
        starts[pb * 4097 + base + q] = v;
        cursor[pb * R2 + base + q] = v;
    }
    if (tid == 255) starts[pb * 4097 + 4096] = part[256];
}

__global__ void k_scatter(const int* __restrict__ i0, const int* __restrict__ i1,
                          const int* __restrict__ i2, int* __restrict__ cursor,
                          unsigned short* __restrict__ order)
{
    int t = blockIdx.x * 256 + threadIdx.x;
    if (t >= NPTS) return;
    int b = t / TPTS;
    int tt = t - b * TPTS;
    int s0 = atomicAdd(&cursor[(0 * BATCH + b) * R2 + i0[t]], 1);
    order[(0 * BATCH + b) * TPTS + s0] = (unsigned short)tt;
    int s1 = atomicAdd(&cursor[(1 * BATCH + b) * R2 + i1[t]], 1);
    order[(1 * BATCH + b) * TPTS + s1] = (unsigned short)tt;
    int s2 = atomicAdd(&cursor[(2 * BATCH + b) * R2 + i2[t]], 1);
    order[(2 * BATCH + b) * TPTS + s2] = (unsigned short)tt;
}

// ---------- gather-based pool max over bf16 net: one wave per bin ----------
__global__ __launch_bounds__(256) void k_poolmax(
    const short* __restrict__ net, const int* __restrict__ starts,
    const unsigned short* __restrict__ order, short* __restrict__ seg)
{
    int pb = blockIdx.y;
    int bin = blockIdx.x * 4 + (threadIdx.x >> 6);
    int lane = threadIdx.x & 63;
    int s = starts[pb * 4097 + bin], e = starts[pb * 4097 + bin + 1];
    if (s == e) return;                       // empty bins never gathered
    int b = pb & 7;
    const unsigned short* ord = order + pb * TPTS;
    float vx = -FLT_MAX, vy = -FLT_MAX;
    for (int i = s; i < e; ++i) {
        int t = b * TPTS + ord[i];
        unsigned u = *(const unsigned*)(net + t * HID + lane * 2);
        vx = fmaxf(vx, bf2f((unsigned short)(u & 0xFFFF)));
        vy = fmaxf(vy, bf2f((unsigned short)(u >> 16)));
    }
    unsigned o = ((unsigned short)f2bf(vx)) | (((unsigned)(unsigned short)f2bf(vy)) << 16);
    *(unsigned*)(seg + (pb * R2 + bin) * HID + lane * 2) = o;
}

// ---------- gather-based pool mean over bf16 c: write f32 seg ----------
__global__ __launch_bounds__(256) void k_poolmean(
    const short* __restrict__ cfeat, const int* __restrict__ starts,
    const unsigned short* __restrict__ order, float* __restrict__ segf)
{
    int pb = blockIdx.y;
    int bin = blockIdx.x * 4 + (threadIdx.x >> 6);
    int lane = threadIdx.x & 63;
    int s = starts[pb * 4097 + bin], e = starts[pb * 4097 + bin + 1];
    int b = pb & 7;
    const unsigned short* ord = order + pb * TPTS;
    float vx = 0.f, vy = 0.f;
    for (int i = s; i < e; ++i) {
        int t = b * TPTS + ord[i];
        unsigned u = *(const unsigned*)(cfeat + t * HID + lane * 2);
        vx += bf2f((unsigned short)(u & 0xFFFF));
        vy += bf2f((unsigned short)(u >> 16));
    }
    float inv = 1.f / fmaxf((float)(e - s), 1.f);
    float2 v = make_float2(vx * inv, vy * inv);
    *(float2*)(segf + (pb * R2 + bin) * HID + lane * 2) = v;   // empty bins -> 0
}

// ---------- resnet body: single xs buffer, in-place relu between S and F phases ----------
__device__ __forceinline__ void resnet_body(
    short* xs, const float* b0s, const float* b1s,
    const short* __restrict__ Wt0r, const short* __restrict__ Wtsr,
    const short* __restrict__ Wt1r, short* __restrict__ net_out, int t0)
{
    int tid = threadIdx.x;
    int lane = tid & 63;
    int wave = tid >> 6;
    int n    = lane & 15;
    int quad = lane >> 4;
    int ch0  = wave * 32;

    // phase S: shortcut = x @ wsc  (raw x in LDS)
    f32x4 accS[2][4] = {};
    for (int ks = 0; ks < 8; ++ks) {
        int ko = ks * 32 + quad * 8;
        short8 aS[2];
#pragma unroll
        for (int c = 0; c < 2; ++c)
            aS[c] = *(const short8*)(Wtsr + (ch0 + c * 16 + n) * 256 + ko);
#pragma unroll
        for (int p = 0; p < 4; ++p) {
            short8 bX = *(const short8*)(xs + (p * 16 + n) * XS + ko);
#pragma unroll
            for (int c = 0; c < 2; ++c)
                accS[c][p] = __builtin_amdgcn_mfma_f32_16x16x32_bf16(aS[c], bX, accS[c][p], 0, 0, 0);
        }
    }
    __syncthreads();

    // in-place relu over the 64x256 payload (pad untouched)
    for (int c8 = tid; c8 < 2048; c8 += 256) {
        int row = c8 >> 5, col = (c8 & 31) << 3;
        uint4* p4 = (uint4*)&xs[row * XS + col];
        uint4 u = *p4;
        u.x = relu2(u.x); u.y = relu2(u.y); u.z = relu2(u.z); u.w = relu2(u.w);
        *p4 = u;
    }
    __syncthreads();

    // phase F: net0 = relu(x) @ w0
    f32x4 accF[2][4] = {};
    for (int ks = 0; ks < 8; ++ks) {
        int ko = ks * 32 + quad * 8;
        short8 aF[2];
#pragma unroll
        for (int c = 0; c < 2; ++c)
            aF[c] = *(const short8*)(Wt0r + (ch0 + c * 16 + n) * 256 + ko);
#pragma unroll
        for (int p = 0; p < 4; ++p) {
            short8 bR = *(const short8*)(xs + (p * 16 + n) * XS + ko);
#pragma unroll
            for (int c = 0; c < 2; ++c)
                accF[c][p] = __builtin_amdgcn_mfma_f32_16x16x32_bf16(aF[c], bR, accF[c][p], 0, 0, 0);
        }
    }
    __syncthreads();   // all xs reads done; safe to alias h

    short* h = xs;
#pragma unroll
    for (int c = 0; c < 2; ++c) {
        int chb = ch0 + c * 16 + quad * 4;
#pragma unroll
        for (int p = 0; p < 4; ++p) {
            int pt = p * 16 + n;
            short4v hv;
#pragma unroll
            for (int r = 0; r < 4; ++r)
                hv[r] = f2bf(fmaxf(accF[c][p][r] + b0s[chb + r], 0.f));
            *(short4v*)&h[pt * HS + chb] = hv;
        }
    }
    __syncthreads();

    // phase 2: accS += h @ w1
    for (int ks = 0; ks < 4; ++ks) {
        int ko = ks * 32 + quad * 8;
        short8 a1[2];
#pragma unroll
        for (int c = 0; c < 2; ++c)
            a1[c] = *(const short8*)(Wt1r + (ch0 + c * 16 + n) * 128 + ko);
#pragma unroll
        for (int p = 0; p < 4; ++p) {
            short8 bh = *(const short8*)&h[(p * 16 + n) * HS + ko];
#pragma unroll
            for (int c = 0; c < 2; ++c)
                accS[c][p] = __builtin_amdgcn_mfma_f32_16x16x32_bf16(a1[c], bh, accS[c][p], 0, 0, 0);
        }
    }

    // epilogue: net_out bf16
#pragma unroll
    for (int c = 0; c < 2; ++c) {
        int chb = ch0 + c * 16 + quad * 4;
#pragma unroll
        for (int p = 0; p < 4; ++p) {
            int pt = p * 16 + n;
            short4v o;
#pragma unroll
            for (int r = 0; r < 4; ++r)
                o[r] = f2bf(accS[c][p][r] + b1s[chb + r]);
            *(short4v*)(net_out + (t0 + pt) * HID + chb) = o;
        }
    }
}

// ---------- block 0: stage x = pts@Wp+bp (raw bf16), then resnet ----------
__global__ __launch_bounds__(256, 4) void k_mblock0(
    const float* __restrict__ pts, const float* __restrict__ Wp, const float* __restrict__ bp,
    const short* __restrict__ Wt0, const short* __restrict__ Wts, const short* __restrict__ Wt1,
    const float* __restrict__ b0, const float* __restrict__ b1, short* __restrict__ net)
{
    __shared__ short xs[PB * XS];
    __shared__ float b0s[HID], b1s[HID];
    int tid = threadIdx.x;
    int t0 = blockIdx.x * PB;
    if (tid < 128) { b0s[tid] = b0[tid]; b1s[tid] = b1[tid]; }

    int j = tid & 127, half = tid >> 7;
    int col = half * 128 + j;
    float w0 = Wp[col], w1 = Wp[256 + col], w2 = Wp[512 + col];
    float bb = bp[col];
    for (int p = 0; p < PB; ++p) {
        int t = t0 + p;
        float px = pts[t * 3], py = pts[t * 3 + 1], pz = pts[t * 3 + 2];
        float v = fmaf(pz, w2, fmaf(py, w1, fmaf(px, w0, bb)));
        xs[p * XS + col] = f2bf(v);
    }
    __syncthreads();
    resnet_body(xs, b0s, b1s, Wt0, Wts, Wt1, net, t0);
}

// ---------- blocks 1..4: stage x = [net | pooled] (16B vector staging), then resnet ----------
// 16 threads per row (16B chunk each): full 128-short coverage of both halves.
__global__ __launch_bounds__(256, 4) void k_mblock(
    const short* __restrict__ net_in, const short* __restrict__ seg,
    const int* __restrict__ i0, const int* __restrict__ i1, const int* __restrict__ i2,
    const short* __restrict__ Wt0, const short* __restrict__ Wts, const short* __restrict__ Wt1,
    const float* __restrict__ b0, const float* __restrict__ b1, short* __restrict__ net_out)
{
    __shared__ short xs[PB * XS];
    __shared__ float b0s[HID], b1s[HID];
    int tid = threadIdx.x;
    int t0 = blockIdx.x * PB;
    if (tid < 128) { b0s[tid] = b0[tid]; b1s[tid] = b1[tid]; }

    int pr = tid >> 4;          // row within group of 16 (16 rows per iter)
    int l8 = (tid & 15) * 8;    // short offset of 16B chunk: 0..120
#pragma unroll
    for (int it = 0; it < 4; ++it) {
        int p = it * 16 + pr;
        int t = t0 + p;
        int bb = t / TPTS;
        int a0 = i0[t], a1 = i1[t], a2 = i2[t];
        // raw net copy (already bf16); wave reads a contiguous 1KB block
        *(short8*)&xs[p * XS + l8] = *(const short8*)(net_in + t * HID + l8);
        // pooled = sum of 3 plane maxima
        short8 s0 = *(const short8*)(seg + ((0 * BATCH + bb) * R2 + a0) * HID + l8);
        short8 s1 = *(const short8*)(seg + ((1 * BATCH + bb) * R2 + a1) * HID + l8);
        short8 s2 = *(const short8*)(seg + ((2 * BATCH + bb) * R2 + a2) * HID + l8);
        short8 pv;
#pragma unroll
        for (int r = 0; r < 8; ++r)
            pv[r] = f2bf(bf2f((unsigned short)s0[r]) + bf2f((unsigned short)s1[r]) + bf2f((unsigned short)s2[r]));
        *(short8*)&xs[p * XS + 128 + l8] = pv;
    }
    __syncthreads();
    resnet_body(xs, b0s, b1s, Wt0, Wts, Wt1, net_out, t0);
}

// ---------- final projection c = net@Wc + bc via MFMA, in-place bf16 ----------
__global__ __launch_bounds__(256, 4) void k_finalm(
    short* __restrict__ net, const short* __restrict__ Wtc, const float* __restrict__ bc)
{
    __shared__ short hbuf[PB * HS];
    __shared__ float bcs[HID];
    int tid = threadIdx.x;
    int t0 = blockIdx.x * PB;
    if (tid < 128) bcs[tid] = bc[tid];
    // stage 64 rows x 128 bf16 (direct copy)
    for (int c8 = tid; c8 < 1024; c8 += 256) {
        int p = c8 >> 4, l = (c8 & 15) * 8;
        *(short8*)&hbuf[p * HS + l] = *(const short8*)(net + (t0 + p) * HID + l);
    }
    __syncthreads();

    int lane = tid & 63, wave = tid >> 6;
    int n = lane & 15, quad = lane >> 4;
    int ch0 = wave * 32;
    f32x4 acc[2][4] = {};
    for (int ks = 0; ks < 4; ++ks) {
        int ko = ks * 32 + quad * 8;
        short8 a[2];
#pragma unroll
        for (int c = 0; c < 2; ++c)
            a[c] = *(const short8*)(Wtc + (ch0 + c * 16 + n) * 128 + ko);
#pragma unroll
        for (int p = 0; p < 4; ++p) {
            short8 bh = *(const short8*)&hbuf[(p * 16 + n) * HS + ko];
#pragma unroll
            for (int c = 0; c < 2; ++c)
                acc[c][p] = __builtin_amdgcn_mfma_f32_16x16x32_bf16(a[c], bh, acc[c][p], 0, 0, 0);
        }
    }
#pragma unroll
    for (int c = 0; c < 2; ++c) {
        int chb = ch0 + c * 16 + quad * 4;
#pragma unroll
        for (int p = 0; p < 4; ++p) {
            int pt = p * 16 + n;
            short4v o;
#pragma unroll
            for (int r = 0; r < 4; ++r)
                o[r] = f2bf(acc[c][p][r] + bcs[chb + r]);
            *(short4v*)(net + (t0 + pt) * HID + chb) = o;
        }
    }
}

// ---------- transpose [pb][bin][ch] f32 -> out [pb][ch][bin], LDS-tiled ----------
__global__ __launch_bounds__(256) void k_norm(
    const float* __restrict__ segf, float* __restrict__ out)
{
    __shared__ float tile[64 * 132];
    int pb = blockIdx.y;
    int bin0 = blockIdx.x * 64;
    int tid = threadIdx.x;
    // read 64 bins x 128 ch, coalesced float4
    for (int c4 = tid; c4 < 2048; c4 += 256) {
        int row = c4 >> 5, col = (c4 & 31) * 4;
        float4 v = *(const float4*)(segf + (pb * R2 + bin0 + row) * HID + col);
        *(float4*)&tile[row * 132 + col] = v;
    }
    __syncthreads();
    // write 128 ch x 64 bins, coalesced float4
    for (int c4 = tid; c4 < 2048; c4 += 256) {
        int ch = c4 >> 4, b4 = (c4 & 15) * 4;
        float4 o;
        o.x = tile[(b4 + 0) * 132 + ch];
        o.y = tile[(b4 + 1) * 132 + ch];
        o.z = tile[(b4 + 2) * 132 + ch];
        o.w = tile[(b4 + 3) * 132 + ch];
        *(float4*)(out + (pb * 128 + ch) * R2 + bin0 + b4) = o;
    }
}

extern "C" void kernel_launch(void* const* d_in, const int* in_sizes, int n_in,
                              void* d_out, int out_size, void* d_ws, size_t ws_size,
                              hipStream_t stream) {
    const float* pts  = (const float*)d_in[0];
    const int*   ixz  = (const int*)d_in[1];
    const int*   ixy  = (const int*)d_in[2];
    const int*   iyz  = (const int*)d_in[3];
    const float* Wp   = (const float*)d_in[4];
    const float* bp   = (const float*)d_in[5];
    const float* fc0w = (const float*)d_in[6];
    const float* fc0b = (const float*)d_in[7];
    const float* fc1w = (const float*)d_in[8];
    const float* fc1b = (const float*)d_in[9];
    const float* scw  = (const float*)d_in[10];
    const float* Wc   = (const float*)d_in[11];
    const float* bc   = (const float*)d_in[12];
    float* out = (float*)d_out;

    short* Wt0 = (short*)d_ws;             // 163840
    short* Wts = Wt0 + 163840;             // 163840
    short* Wt1 = Wts + 163840;             // 81920
    short* Wtc = Wt1 + 81920;              // 16384   (total 425984 shorts)
    short* net  = Wtc + 16384;             // 30,720,000 shorts (61.4 MB), bf16
    short* segb = net + 30720000;          // 12,582,912 shorts (25.2 MB), bf16
    float* segf = (float*)(segb + 12582912);  // 12,582,912 floats (50.3 MB)
    int* hist   = (int*)(segf + 12582912); // 98304 (doubles as cursor)
    int* starts = hist + 98304;            // 24*4097
    unsigned short* order = (unsigned short*)(starts + 98328); // 720000

    k_prep<<<dim3(640), 256, 0, stream>>>(fc0w, fc1w, scw, Wc, Wt0, Wts, Wt1, Wtc);
    k_fill4<<<dim3(96), 256, 0, stream>>>((float4*)hist, 0.f, 98304 / 4);
    k_hist<<<dim3((NPTS + 255) / 256), 256, 0, stream>>>(ixz, ixy, iyz, hist);
    k_scan<<<dim3(24), 256, 0, stream>>>(hist, starts, hist);
    k_scatter<<<dim3((NPTS + 255) / 256), 256, 0, stream>>>(ixz, ixy, iyz, hist, order);

    k_mblock0<<<dim3(NPTS / PB), 256, 0, stream>>>(pts, Wp, bp, Wt0, Wts, Wt1, fc0b, fc1b, net);

    for (int r = 1; r < 5; ++r) {
        k_poolmax<<<dim3(R2 / 4, 24), 256, 0, stream>>>(net, starts, order, segb);
        k_mblock<<<dim3(NPTS / PB), 256, 0, stream>>>(
            net, segb, ixz, ixy, iyz,
            Wt0 + r * 32768, Wts + r * 32768, Wt1 + r * 16384,
            fc0b + r * 128, fc1b + r * 128, net);
    }

    k_finalm<<<dim3(NPTS / PB), 256, 0, stream>>>(net, Wtc, bc);
    k_poolmean<<<dim3(R2 / 4, 24), 256, 0, stream>>>(net, starts, order, segf);
    k_norm<<<dim3(R2 / 64, 24), 256, 0, stream>>>(segf, out);
}

// Round 6
// 1301.572 us; speedup vs baseline: 5.2365x; 1.0081x over previous
//
#include <hip/hip_runtime.h>
#include <float.h>

#define BATCH 8
#define TPTS 30000
#define HID 128
#define R2 4096
#define NPTS (BATCH * TPTS)   // 240000
#define PB 64                 // points per block
#define XS 264                // xs row stride in bf16 elems (256 + 8 pad)
#define HS 136                // h row stride (128 + 8 pad)

typedef __attribute__((ext_vector_type(8))) short short8;
typedef __attribute__((ext_vector_type(4))) short short4v;
typedef __attribute__((ext_vector_type(4))) float f32x4;

__device__ __forceinline__ short f2bf(float f) {
    unsigned u = __float_as_uint(f);
    u += 0x7fff + ((u >> 16) & 1);   // RNE
    return (short)(u >> 16);
}
__device__ __forceinline__ float bf2f(unsigned short u) {
    return __uint_as_float(((unsigned)u) << 16);
}
// packed relu on two bf16 in one dword: negative -> sign-only (-0.0, harmless as matmul input)
__device__ __forceinline__ unsigned relu2(unsigned u) {
    unsigned sm = u & 0x80008000u;
    unsigned d  = sm - (sm >> 15);
    return u & ~d;
}

__global__ void k_fill4(float4* p, float v, int n4) {
    int i = blockIdx.x * blockDim.x + threadIdx.x;
    if (i < n4) p[i] = make_float4(v, v, v, v);
}

// ---------- weight prep: f32 [k][ch] -> bf16 transposed [ch][k] ----------
__global__ __launch_bounds__(256) void k_prep(
    const float* __restrict__ fc0w, const float* __restrict__ fc1w, const float* __restrict__ scw,
    const float* __restrict__ fccw,
    short* __restrict__ Wt0, short* __restrict__ Wts, short* __restrict__ Wt1,
    short* __restrict__ Wtc)
{
    int i = blockIdx.x * 256 + threadIdx.x;
    if (i < 5 * 128 * 256) {
        int r = i >> 15;
        int c = (i >> 8) & 127;
        int k = i & 255;
        Wt0[i] = f2bf(fc0w[(r * 256 + k) * 128 + c]);
        Wts[i] = f2bf(scw [(r * 256 + k) * 128 + c]);
    }
    if (i < 5 * 128 * 128) {
        int r = i >> 14;
        int c = (i >> 7) & 127;
        int k = i & 127;
        Wt1[i] = f2bf(fc1w[(r * 128 + k) * 128 + c]);
    }
    if (i < 128 * 128) {
        int c = (i >> 7) & 127;
        int k = i & 127;
        Wtc[i] = f2bf(fccw[k * 128 + c]);
    }
}

// ---------- counting sort of points by bin (per plane, per batch) ----------
__global__ void k_hist(const int* __restrict__ i0, const int* __restrict__ i1,
                       const int* __restrict__ i2, int* __restrict__ hist)
{
    int t = blockIdx.x * 256 + threadIdx.x;
    if (t >= NPTS) return;
    int b = t / TPTS;
    atomicAdd(&hist[(0 * BATCH + b) * R2 + i0[t]], 1);
    atomicAdd(&hist[(1 * BATCH + b) * R2 + i1[t]], 1);
    atomicAdd(&hist[(2 * BATCH + b) * R2 + i2[t]], 1);
}

__global__ __launch_bounds__(256) void k_scan(const int* __restrict__ hist,
                                              int* __restrict__ starts, int* __restrict__ cursor)
{
    int pb = blockIdx.x;                 // 0..23
    const int* h = hist + pb * R2;
    int tid = threadIdx.x;
    __shared__ int part[257];
    int loc[16]; int s = 0;
    int base = tid * 16;
#pragma unroll
    for (int q = 0; q < 16; ++q) { loc[q] = s; s += h[base + q]; }
    part[tid + 1] = s;
    __syncthreads();
    if (tid == 0) {
        part[0] = 0;
        for (int i = 1; i <= 256; ++i) part[i] += part[i - 1];
    }
    __syncthreads();
    int off = part[tid];
#pragma unroll
    for (int q = 0; q < 16; ++q) {
        int v = off + loc[q];
        starts[pb * 4097 + base + q] = v;
        cursor[pb * R2 + base + q] = v;
    }
    if (tid == 255) starts[pb * 4097 + 4096] = part[256];
}

__global__ void k_scatter(const int* __restrict__ i0, const int* __restrict__ i1,
                          const int* __restrict__ i2, int* __restrict__ cursor,
                          unsigned short* __restrict__ order)
{
    int t = blockIdx.x * 256 + threadIdx.x;
    if (t >= NPTS) return;
    int b = t / TPTS;
    int tt = t - b * TPTS;
    int s0 = atomicAdd(&cursor[(0 * BATCH + b) * R2 + i0[t]], 1);
    order[(0 * BATCH + b) * TPTS + s0] = (unsigned short)tt;
    int s1 = atomicAdd(&cursor[(1 * BATCH + b) * R2 + i1[t]], 1);
    order[(1 * BATCH + b) * TPTS + s1] = (unsigned short)tt;
    int s2 = atomicAdd(&cursor[(2 * BATCH + b) * R2 + i2[t]], 1);
    order[(2 * BATCH + b) * TPTS + s2] = (unsigned short)tt;
}

// ---------- gather-based pool max over bf16 net: one wave per bin ----------
__global__ __launch_bounds__(256) void k_poolmax(
    const short* __restrict__ net, const int* __restrict__ starts,
    const unsigned short* __restrict__ order, short* __restrict__ seg)
{
    int pb = blockIdx.y;
    int bin = blockIdx.x * 4 + (threadIdx.x >> 6);
    int lane = threadIdx.x & 63;
    int s = starts[pb * 4097 + bin], e = starts[pb * 4097 + bin + 1];
    if (s == e) return;                       // empty bins never gathered
    int b = pb & 7;
    const unsigned short* ord = order + pb * TPTS;
    float vx = -FLT_MAX, vy = -FLT_MAX;
    for (int i = s; i < e; ++i) {
        int t = b * TPTS + ord[i];
        unsigned u = *(const unsigned*)(net + t * HID + lane * 2);
        vx = fmaxf(vx, bf2f((unsigned short)(u & 0xFFFF)));
        vy = fmaxf(vy, bf2f((unsigned short)(u >> 16)));
    }
    unsigned o = ((unsigned short)f2bf(vx)) | (((unsigned)(unsigned short)f2bf(vy)) << 16);
    *(unsigned*)(seg + (pb * R2 + bin) * HID + lane * 2) = o;
}

// ---------- gather-based pool mean over bf16 net -> bf16 means [pb][bin][128] ----------
__global__ __launch_bounds__(256) void k_poolmean(
    const short* __restrict__ net, const int* __restrict__ starts,
    const unsigned short* __restrict__ order, short* __restrict__ meanb)
{
    int pb = blockIdx.y;
    int bin = blockIdx.x * 4 + (threadIdx.x >> 6);
    int lane = threadIdx.x & 63;
    int s = starts[pb * 4097 + bin], e = starts[pb * 4097 + bin + 1];
    int b = pb & 7;
    const unsigned short* ord = order + pb * TPTS;
    float vx = 0.f, vy = 0.f;
    for (int i = s; i < e; ++i) {
        int t = b * TPTS + ord[i];
        unsigned u = *(const unsigned*)(net + t * HID + lane * 2);
        vx += bf2f((unsigned short)(u & 0xFFFF));
        vy += bf2f((unsigned short)(u >> 16));
    }
    float inv = 1.f / fmaxf((float)(e - s), 1.f);
    unsigned o = ((unsigned short)f2bf(vx * inv)) | (((unsigned)(unsigned short)f2bf(vy * inv)) << 16);
    *(unsigned*)(meanb + (pb * R2 + bin) * HID + lane * 2) = o;   // empty bins -> 0
}

// ---------- resnet body: single xs buffer, in-place relu, coalesced epilogue ----------
__device__ __forceinline__ void resnet_body(
    short* xs, const float* b0s, const float* b1s,
    const short* __restrict__ Wt0r, const short* __restrict__ Wtsr,
    const short* __restrict__ Wt1r, short* __restrict__ net_out, int t0)
{
    int tid = threadIdx.x;
    int lane = tid & 63;
    int wave = tid >> 6;
    int n    = lane & 15;
    int quad = lane >> 4;
    int ch0  = wave * 32;

    // phase S: shortcut = x @ wsc  (raw x in LDS)
    f32x4 accS[2][4] = {};
    for (int ks = 0; ks < 8; ++ks) {
        int ko = ks * 32 + quad * 8;
        short8 aS[2];
#pragma unroll
        for (int c = 0; c < 2; ++c)
            aS[c] = *(const short8*)(Wtsr + (ch0 + c * 16 + n) * 256 + ko);
#pragma unroll
        for (int p = 0; p < 4; ++p) {
            short8 bX = *(const short8*)(xs + (p * 16 + n) * XS + ko);
#pragma unroll
            for (int c = 0; c < 2; ++c)
                accS[c][p] = __builtin_amdgcn_mfma_f32_16x16x32_bf16(aS[c], bX, accS[c][p], 0, 0, 0);
        }
    }
    __syncthreads();

    // in-place relu over the 64x256 payload (pad untouched)
    for (int c8 = tid; c8 < 2048; c8 += 256) {
        int row = c8 >> 5, col = (c8 & 31) << 3;
        uint4* p4 = (uint4*)&xs[row * XS + col];
        uint4 u = *p4;
        u.x = relu2(u.x); u.y = relu2(u.y); u.z = relu2(u.z); u.w = relu2(u.w);
        *p4 = u;
    }
    __syncthreads();

    // phase F: net0 = relu(x) @ w0
    f32x4 accF[2][4] = {};
    for (int ks = 0; ks < 8; ++ks) {
        int ko = ks * 32 + quad * 8;
        short8 aF[2];
#pragma unroll
        for (int c = 0; c < 2; ++c)
            aF[c] = *(const short8*)(Wt0r + (ch0 + c * 16 + n) * 256 + ko);
#pragma unroll
        for (int p = 0; p < 4; ++p) {
            short8 bR = *(const short8*)(xs + (p * 16 + n) * XS + ko);
#pragma unroll
            for (int c = 0; c < 2; ++c)
                accF[c][p] = __builtin_amdgcn_mfma_f32_16x16x32_bf16(aF[c], bR, accF[c][p], 0, 0, 0);
        }
    }
    __syncthreads();   // all xs reads done; safe to alias h

    short* h = xs;
#pragma unroll
    for (int c = 0; c < 2; ++c) {
        int chb = ch0 + c * 16 + quad * 4;
#pragma unroll
        for (int p = 0; p < 4; ++p) {
            int pt = p * 16 + n;
            short4v hv;
#pragma unroll
            for (int r = 0; r < 4; ++r)
                hv[r] = f2bf(fmaxf(accF[c][p][r] + b0s[chb + r], 0.f));
            *(short4v*)&h[pt * HS + chb] = hv;
        }
    }
    __syncthreads();

    // phase 2: accS += h @ w1
    for (int ks = 0; ks < 4; ++ks) {
        int ko = ks * 32 + quad * 8;
        short8 a1[2];
#pragma unroll
        for (int c = 0; c < 2; ++c)
            a1[c] = *(const short8*)(Wt1r + (ch0 + c * 16 + n) * 128 + ko);
#pragma unroll
        for (int p = 0; p < 4; ++p) {
            short8 bh = *(const short8*)&h[(p * 16 + n) * HS + ko];
#pragma unroll
            for (int c = 0; c < 2; ++c)
                accS[c][p] = __builtin_amdgcn_mfma_f32_16x16x32_bf16(a1[c], bh, accS[c][p], 0, 0, 0);
        }
    }
    __syncthreads();   // h reads done; reuse h for the output tile

    // epilogue stage 1: accS + b1 -> LDS (bf16, h layout)
#pragma unroll
    for (int c = 0; c < 2; ++c) {
        int chb = ch0 + c * 16 + quad * 4;
#pragma unroll
        for (int p = 0; p < 4; ++p) {
            int pt = p * 16 + n;
            short4v o;
#pragma unroll
            for (int r = 0; r < 4; ++r)
                o[r] = f2bf(accS[c][p][r] + b1s[chb + r]);
            *(short4v*)&h[pt * HS + chb] = o;
        }
    }
    __syncthreads();

    // epilogue stage 2: coalesced store — wave writes 4 consecutive rows = 1KB contiguous
    int pr = tid >> 4, l8 = (tid & 15) * 8;
#pragma unroll
    for (int it = 0; it < 4; ++it) {
        int p = it * 16 + pr;
        *(short8*)(net_out + (t0 + p) * HID + l8) = *(const short8*)&h[p * HS + l8];
    }
}

// ---------- block 0: stage x = pts@Wp+bp (raw bf16), then resnet ----------
__global__ __launch_bounds__(256, 4) void k_mblock0(
    const float* __restrict__ pts, const float* __restrict__ Wp, const float* __restrict__ bp,
    const short* __restrict__ Wt0, const short* __restrict__ Wts, const short* __restrict__ Wt1,
    const float* __restrict__ b0, const float* __restrict__ b1, short* __restrict__ net)
{
    __shared__ short xs[PB * XS];
    __shared__ float b0s[HID], b1s[HID];
    int tid = threadIdx.x;
    int t0 = blockIdx.x * PB;
    if (tid < 128) { b0s[tid] = b0[tid]; b1s[tid] = b1[tid]; }

    int j = tid & 127, half = tid >> 7;
    int col = half * 128 + j;
    float w0 = Wp[col], w1 = Wp[256 + col], w2 = Wp[512 + col];
    float bb = bp[col];
    for (int p = 0; p < PB; ++p) {
        int t = t0 + p;
        float px = pts[t * 3], py = pts[t * 3 + 1], pz = pts[t * 3 + 2];
        float v = fmaf(pz, w2, fmaf(py, w1, fmaf(px, w0, bb)));
        xs[p * XS + col] = f2bf(v);
    }
    __syncthreads();
    resnet_body(xs, b0s, b1s, Wt0, Wts, Wt1, net, t0);
}

// ---------- blocks 1..4: stage x = [net | pooled] (16B vector staging), then resnet ----------
__global__ __launch_bounds__(256, 4) void k_mblock(
    const short* __restrict__ net_in, const short* __restrict__ seg,
    const int* __restrict__ i0, const int* __restrict__ i1, const int* __restrict__ i2,
    const short* __restrict__ Wt0, const short* __restrict__ Wts, const short* __restrict__ Wt1,
    const float* __restrict__ b0, const float* __restrict__ b1, short* __restrict__ net_out)
{
    __shared__ short xs[PB * XS];
    __shared__ float b0s[HID], b1s[HID];
    int tid = threadIdx.x;
    int t0 = blockIdx.x * PB;
    if (tid < 128) { b0s[tid] = b0[tid]; b1s[tid] = b1[tid]; }

    int pr = tid >> 4;          // row within group of 16 (16 rows per iter)
    int l8 = (tid & 15) * 8;    // short offset of 16B chunk: 0..120
#pragma unroll
    for (int it = 0; it < 4; ++it) {
        int p = it * 16 + pr;
        int t = t0 + p;
        int bb = t / TPTS;
        int a0 = i0[t], a1 = i1[t], a2 = i2[t];
        // raw net copy (already bf16); wave reads a contiguous 1KB block
        *(short8*)&xs[p * XS + l8] = *(const short8*)(net_in + t * HID + l8);
        // pooled = sum of 3 plane maxima
        short8 s0 = *(const short8*)(seg + ((0 * BATCH + bb) * R2 + a0) * HID + l8);
        short8 s1 = *(const short8*)(seg + ((1 * BATCH + bb) * R2 + a1) * HID + l8);
        short8 s2 = *(const short8*)(seg + ((2 * BATCH + bb) * R2 + a2) * HID + l8);
        short8 pv;
#pragma unroll
        for (int r = 0; r < 8; ++r)
            pv[r] = f2bf(bf2f((unsigned short)s0[r]) + bf2f((unsigned short)s1[r]) + bf2f((unsigned short)s2[r]));
        *(short8*)&xs[p * XS + 128 + l8] = pv;
    }
    __syncthreads();
    resnet_body(xs, b0s, b1s, Wt0, Wts, Wt1, net_out, t0);
}

// ---------- out = (means @ Wc + bc)^T per plane-batch, empty bins -> 0 ----------
// one block per (pb, 64-bin tile); D[ch][bin] built in LDS then stored coalesced
__global__ __launch_bounds__(256) void k_gemmout(
    const short* __restrict__ meanb, const short* __restrict__ Wtc, const float* __restrict__ bc,
    const int* __restrict__ starts, float* __restrict__ out)
{
    __shared__ short bs[64 * HS];      // means bf16 [bin][k]
    __shared__ float tile[128 * 66];   // output f32 [ch][bin]
    __shared__ float bcs[HID];
    __shared__ int   flg[64];
    int tid = threadIdx.x;
    int pb = blockIdx.y;
    int bin0 = blockIdx.x * 64;

    if (tid < 128) bcs[tid] = bc[tid];
    if (tid < 64)  flg[tid] = (starts[pb * 4097 + bin0 + tid + 1] > starts[pb * 4097 + bin0 + tid]);
    for (int c8 = tid; c8 < 1024; c8 += 256) {
        int p = c8 >> 4, l = (c8 & 15) * 8;
        *(short8*)&bs[p * HS + l] = *(const short8*)(meanb + (pb * R2 + bin0 + p) * HID + l);
    }
    __syncthreads();

    int lane = tid & 63, wave = tid >> 6;
    int n = lane & 15, quad = lane >> 4;
    int ch0 = wave * 32;
    f32x4 acc[2][4] = {};
    for (int ks = 0; ks < 4; ++ks) {
        int ko = ks * 32 + quad * 8;
        short8 a[2];
#pragma unroll
        for (int c = 0; c < 2; ++c)
            a[c] = *(const short8*)(Wtc + (ch0 + c * 16 + n) * 128 + ko);
#pragma unroll
        for (int p = 0; p < 4; ++p) {
            short8 bh = *(const short8*)&bs[(p * 16 + n) * HS + ko];
#pragma unroll
            for (int c = 0; c < 2; ++c)
                acc[c][p] = __builtin_amdgcn_mfma_f32_16x16x32_bf16(a[c], bh, acc[c][p], 0, 0, 0);
        }
    }
    // frag (c,p,r): element (ch = ch0+c*16+quad*4+r, bin = p*16+n)
#pragma unroll
    for (int c = 0; c < 2; ++c) {
        int chb = ch0 + c * 16 + quad * 4;
#pragma unroll
        for (int p = 0; p < 4; ++p) {
            int bin = p * 16 + n;
#pragma unroll
            for (int r = 0; r < 4; ++r)
                tile[(chb + r) * 66 + bin] = acc[c][p][r] + bcs[chb + r];
        }
    }
    __syncthreads();

    // coalesced store: 16 lanes per ch row (float4 each), mask empty bins to 0
    for (int c4 = tid; c4 < 2048; c4 += 256) {
        int ch = c4 >> 4, b4 = (c4 & 15) * 4;
        float4 o;
        o.x = flg[b4 + 0] ? tile[ch * 66 + b4 + 0] : 0.f;
        o.y = flg[b4 + 1] ? tile[ch * 66 + b4 + 1] : 0.f;
        o.z = flg[b4 + 2] ? tile[ch * 66 + b4 + 2] : 0.f;
        o.w = flg[b4 + 3] ? tile[ch * 66 + b4 + 3] : 0.f;
        *(float4*)(out + (pb * 128 + ch) * R2 + bin0 + b4) = o;
    }
}

extern "C" void kernel_launch(void* const* d_in, const int* in_sizes, int n_in,
                              void* d_out, int out_size, void* d_ws, size_t ws_size,
                              hipStream_t stream) {
    const float* pts  = (const float*)d_in[0];
    const int*   ixz  = (const int*)d_in[1];
    const int*   ixy  = (const int*)d_in[2];
    const int*   iyz  = (const int*)d_in[3];
    const float* Wp   = (const float*)d_in[4];
    const float* bp   = (const float*)d_in[5];
    const float* fc0w = (const float*)d_in[6];
    const float* fc0b = (const float*)d_in[7];
    const float* fc1w = (const float*)d_in[8];
    const float* fc1b = (const float*)d_in[9];
    const float* scw  = (const float*)d_in[10];
    const float* Wc   = (const float*)d_in[11];
    const float* bc   = (const float*)d_in[12];
    float* out = (float*)d_out;

    short* Wt0 = (short*)d_ws;             // 163840
    short* Wts = Wt0 + 163840;             // 163840
    short* Wt1 = Wts + 163840;             // 81920
    short* Wtc = Wt1 + 81920;              // 16384   (total 425984 shorts)
    short* net  = Wtc + 16384;             // 30,720,000 shorts (61.4 MB), bf16
    short* segb = net + 30720000;          // 12,582,912 shorts (25.2 MB), bf16 (pool max / means)
    int* hist   = (int*)(segb + 12582912); // 98304 (doubles as cursor)
    int* starts = hist + 98304;            // 24*4097
    unsigned short* order = (unsigned short*)(starts + 98328); // 720000

    k_prep<<<dim3(640), 256, 0, stream>>>(fc0w, fc1w, scw, Wc, Wt0, Wts, Wt1, Wtc);
    k_fill4<<<dim3(96), 256, 0, stream>>>((float4*)hist, 0.f, 98304 / 4);
    k_hist<<<dim3((NPTS + 255) / 256), 256, 0, stream>>>(ixz, ixy, iyz, hist);
    k_scan<<<dim3(24), 256, 0, stream>>>(hist, starts, hist);
    k_scatter<<<dim3((NPTS + 255) / 256), 256, 0, stream>>>(ixz, ixy, iyz, hist, order);

    k_mblock0<<<dim3(NPTS / PB), 256, 0, stream>>>(pts, Wp, bp, Wt0, Wts, Wt1, fc0b, fc1b, net);

    for (int r = 1; r < 5; ++r) {
        k_poolmax<<<dim3(R2 / 4, 24), 256, 0, stream>>>(net, starts, order, segb);
        k_mblock<<<dim3(NPTS / PB), 256, 0, stream>>>(
            net, segb, ixz, ixy, iyz,
            Wt0 + r * 32768, Wts + r * 32768, Wt1 + r * 16384,
            fc0b + r * 128, fc1b + r * 128, net);
    }

    // segment_mean(net@Wc+bc) == segment_mean(net)@Wc+bc  (bin means, then tiny GEMM)
    k_poolmean<<<dim3(R2 / 4, 24), 256, 0, stream>>>(net, starts, order, segb);
    k_gemmout<<<dim3(R2 / 64, 24), 256, 0, stream>>>(segb, Wtc, bc, starts, out);
}

// Round 7
// 993.014 us; speedup vs baseline: 6.8637x; 1.3107x over previous
//
#include <hip/hip_runtime.h>
#include <float.h>

#define BATCH 8
#define TPTS 30000
#define NPR 30016             // padded rows per batch (469 * 64)
#define HID 128
#define R2 4096
#define NPTS (BATCH * TPTS)   // 240000
#define PB 64                 // points per block
#define XS 264                // xs row stride in bf16 elems (256 + 8 pad)
#define HS 136                // h row stride (128 + 8 pad)

typedef __attribute__((ext_vector_type(8))) short short8;
typedef __attribute__((ext_vector_type(4))) short short4v;
typedef __attribute__((ext_vector_type(4))) float f32x4;

__device__ __forceinline__ short f2bf(float f) {
    unsigned u = __float_as_uint(f);
    u += 0x7fff + ((u >> 16) & 1);   // RNE
    return (short)(u >> 16);
}
__device__ __forceinline__ float bf2f(unsigned short u) {
    return __uint_as_float(((unsigned)u) << 16);
}
// packed relu on two bf16 in one dword: negative -> sign-only (-0.0, harmless as matmul input)
__device__ __forceinline__ unsigned relu2(unsigned u) {
    unsigned sm = u & 0x80008000u;
    unsigned d  = sm - (sm >> 15);
    return u & ~d;
}
__device__ __forceinline__ short8 relu8(short8 v) {
    union { short8 s; unsigned u[4]; } a;
    a.s = v;
#pragma unroll
    for (int i = 0; i < 4; ++i) a.u[i] = relu2(a.u[i]);
    return a.s;
}

__global__ void k_fill4(float4* p, float v, int n4) {
    int i = blockIdx.x * blockDim.x + threadIdx.x;
    if (i < n4) p[i] = make_float4(v, v, v, v);
}

// ---------- weight prep: f32 [k][ch] -> bf16 transposed [ch][k] ----------
__global__ __launch_bounds__(256) void k_prep(
    const float* __restrict__ fc0w, const float* __restrict__ fc1w, const float* __restrict__ scw,
    const float* __restrict__ fccw,
    short* __restrict__ Wt0, short* __restrict__ Wts, short* __restrict__ Wt1,
    short* __restrict__ Wtc)
{
    int i = blockIdx.x * 256 + threadIdx.x;
    if (i < 5 * 128 * 256) {
        int r = i >> 15;
        int c = (i >> 8) & 127;
        int k = i & 255;
        Wt0[i] = f2bf(fc0w[(r * 256 + k) * 128 + c]);
        Wts[i] = f2bf(scw [(r * 256 + k) * 128 + c]);
    }
    if (i < 5 * 128 * 128) {
        int r = i >> 14;
        int c = (i >> 7) & 127;
        int k = i & 127;
        Wt1[i] = f2bf(fc1w[(r * 128 + k) * 128 + c]);
    }
    if (i < 128 * 128) {
        int c = (i >> 7) & 127;
        int k = i & 127;
        Wtc[i] = f2bf(fccw[k * 128 + c]);
    }
}

// ---------- counting sort of points by bin (per plane, per batch) ----------
__global__ void k_hist(const int* __restrict__ i0, const int* __restrict__ i1,
                       const int* __restrict__ i2, int* __restrict__ hist)
{
    int t = blockIdx.x * 256 + threadIdx.x;
    if (t >= NPTS) return;
    int b = t / TPTS;
    atomicAdd(&hist[(0 * BATCH + b) * R2 + i0[t]], 1);
    atomicAdd(&hist[(1 * BATCH + b) * R2 + i1[t]], 1);
    atomicAdd(&hist[(2 * BATCH + b) * R2 + i2[t]], 1);
}

__global__ __launch_bounds__(256) void k_scan(const int* __restrict__ hist,
                                              int* __restrict__ starts, int* __restrict__ cursor)
{
    int pb = blockIdx.x;                 // 0..23
    const int* h = hist + pb * R2;
    int tid = threadIdx.x;
    __shared__ int part[257];
    int loc[16]; int s = 0;
    int base = tid * 16;
#pragma unroll
    for (int q = 0; q < 16; ++q) { loc[q] = s; s += h[base + q]; }
    part[tid + 1] = s;
    __syncthreads();
    if (tid == 0) {
        part[0] = 0;
        for (int i = 1; i <= 256; ++i) part[i] += part[i - 1];
    }
    __syncthreads();
    int off = part[tid];
#pragma unroll
    for (int q = 0; q < 16; ++q) {
        int v = off + loc[q];
        starts[pb * 4097 + base + q] = v;
        cursor[pb * R2 + base + q] = v;
    }
    if (tid == 255) starts[pb * 4097 + 4096] = part[256];
}

__global__ void k_scatter(const int* __restrict__ i0, const int* __restrict__ i1,
                          const int* __restrict__ i2, int* __restrict__ cursor,
                          unsigned short* __restrict__ order)
{
    int t = blockIdx.x * 256 + threadIdx.x;
    if (t >= NPTS) return;
    int b = t / TPTS;
    int tt = t - b * TPTS;
    int s0 = atomicAdd(&cursor[(0 * BATCH + b) * R2 + i0[t]], 1);
    order[(0 * BATCH + b) * TPTS + s0] = (unsigned short)tt;
    int s1 = atomicAdd(&cursor[(1 * BATCH + b) * R2 + i1[t]], 1);
    order[(1 * BATCH + b) * TPTS + s1] = (unsigned short)tt;
    int s2 = atomicAdd(&cursor[(2 * BATCH + b) * R2 + i2[t]], 1);
    order[(2 * BATCH + b) * TPTS + s2] = (unsigned short)tt;
}

// ---------- gather-based pool max over bf16 net: one wave per bin ----------
// grid (8, 3072): batch = blockIdx.x (XCD affinity), plane/bin from blockIdx.y
__global__ __launch_bounds__(256) void k_poolmax(
    const short* __restrict__ net, const int* __restrict__ starts,
    const unsigned short* __restrict__ order, short* __restrict__ seg)
{
    int b = blockIdx.x;
    int plane = blockIdx.y >> 10;
    int bin = (blockIdx.y & 1023) * 4 + (threadIdx.x >> 6);
    int pb = plane * BATCH + b;
    int lane = threadIdx.x & 63;
    int s = starts[pb * 4097 + bin], e = starts[pb * 4097 + bin + 1];
    if (s == e) return;                       // empty bins never gathered
    const unsigned short* ord = order + pb * TPTS;
    float vx = -FLT_MAX, vy = -FLT_MAX;
    for (int i = s; i < e; ++i) {
        int t = b * NPR + ord[i];
        unsigned u = *(const unsigned*)(net + t * HID + lane * 2);
        vx = fmaxf(vx, bf2f((unsigned short)(u & 0xFFFF)));
        vy = fmaxf(vy, bf2f((unsigned short)(u >> 16)));
    }
    unsigned o = ((unsigned short)f2bf(vx)) | (((unsigned)(unsigned short)f2bf(vy)) << 16);
    *(unsigned*)(seg + (pb * R2 + bin) * HID + lane * 2) = o;
}

// ---------- gather-based pool mean over bf16 net -> bf16 means [pb][bin][128] ----------
__global__ __launch_bounds__(256) void k_poolmean(
    const short* __restrict__ net, const int* __restrict__ starts,
    const unsigned short* __restrict__ order, short* __restrict__ meanb)
{
    int b = blockIdx.x;
    int plane = blockIdx.y >> 10;
    int bin = (blockIdx.y & 1023) * 4 + (threadIdx.x >> 6);
    int pb = plane * BATCH + b;
    int lane = threadIdx.x & 63;
    int s = starts[pb * 4097 + bin], e = starts[pb * 4097 + bin + 1];
    const unsigned short* ord = order + pb * TPTS;
    float vx = 0.f, vy = 0.f;
    for (int i = s; i < e; ++i) {
        int t = b * NPR + ord[i];
        unsigned u = *(const unsigned*)(net + t * HID + lane * 2);
        vx += bf2f((unsigned short)(u & 0xFFFF));
        vy += bf2f((unsigned short)(u >> 16));
    }
    float inv = 1.f / fmaxf((float)(e - s), 1.f);
    unsigned o = ((unsigned short)f2bf(vx * inv)) | (((unsigned)(unsigned short)f2bf(vy * inv)) << 16);
    *(unsigned*)(meanb + (pb * R2 + bin) * HID + lane * 2) = o;   // empty bins -> 0
}

// ---------- resnet body: merged S+F MFMA phase (relu in registers), coalesced epilogue ----------
__device__ __forceinline__ void resnet_body(
    short* xs, const float* b0s, const float* b1s,
    const short* __restrict__ Wt0r, const short* __restrict__ Wtsr,
    const short* __restrict__ Wt1r, short* __restrict__ net_out, int t0)
{
    int tid = threadIdx.x;
    int lane = tid & 63;
    int wave = tid >> 6;
    int n    = lane & 15;
    int quad = lane >> 4;
    int ch0  = wave * 32;

    // merged phase: accS = x @ wsc ; accF = relu(x) @ w0   (one B-load, 4 MFMAs)
    f32x4 accS[2][4] = {};
    f32x4 accF[2][4] = {};
    for (int ks = 0; ks < 8; ++ks) {
        int ko = ks * 32 + quad * 8;
        short8 aS[2], aF[2];
#pragma unroll
        for (int c = 0; c < 2; ++c) {
            int row = ch0 + c * 16 + n;
            aS[c] = *(const short8*)(Wtsr + row * 256 + ko);
            aF[c] = *(const short8*)(Wt0r + row * 256 + ko);
        }
#pragma unroll
        for (int p = 0; p < 4; ++p) {
            short8 bX = *(const short8*)(xs + (p * 16 + n) * XS + ko);
            short8 bR = relu8(bX);
#pragma unroll
            for (int c = 0; c < 2; ++c) {
                accS[c][p] = __builtin_amdgcn_mfma_f32_16x16x32_bf16(aS[c], bX, accS[c][p], 0, 0, 0);
                accF[c][p] = __builtin_amdgcn_mfma_f32_16x16x32_bf16(aF[c], bR, accF[c][p], 0, 0, 0);
            }
        }
    }
    __syncthreads();   // all xs reads done; safe to alias h

    short* h = xs;
#pragma unroll
    for (int c = 0; c < 2; ++c) {
        int chb = ch0 + c * 16 + quad * 4;
#pragma unroll
        for (int p = 0; p < 4; ++p) {
            int pt = p * 16 + n;
            short4v hv;
#pragma unroll
            for (int r = 0; r < 4; ++r)
                hv[r] = f2bf(fmaxf(accF[c][p][r] + b0s[chb + r], 0.f));
            *(short4v*)&h[pt * HS + chb] = hv;
        }
    }
    __syncthreads();

    // phase 2: accS += h @ w1
    for (int ks = 0; ks < 4; ++ks) {
        int ko = ks * 32 + quad * 8;
        short8 a1[2];
#pragma unroll
        for (int c = 0; c < 2; ++c)
            a1[c] = *(const short8*)(Wt1r + (ch0 + c * 16 + n) * 128 + ko);
#pragma unroll
        for (int p = 0; p < 4; ++p) {
            short8 bh = *(const short8*)&h[(p * 16 + n) * HS + ko];
#pragma unroll
            for (int c = 0; c < 2; ++c)
                accS[c][p] = __builtin_amdgcn_mfma_f32_16x16x32_bf16(a1[c], bh, accS[c][p], 0, 0, 0);
        }
    }
    __syncthreads();   // h reads done; reuse h for the output tile

    // epilogue stage 1: accS + b1 -> LDS (bf16, h layout)
#pragma unroll
    for (int c = 0; c < 2; ++c) {
        int chb = ch0 + c * 16 + quad * 4;
#pragma unroll
        for (int p = 0; p < 4; ++p) {
            int pt = p * 16 + n;
            short4v o;
#pragma unroll
            for (int r = 0; r < 4; ++r)
                o[r] = f2bf(accS[c][p][r] + b1s[chb + r]);
            *(short4v*)&h[pt * HS + chb] = o;
        }
    }
    __syncthreads();

    // epilogue stage 2: coalesced store — wave writes 4 consecutive rows = 1KB contiguous
    int pr = tid >> 4, l8 = (tid & 15) * 8;
#pragma unroll
    for (int it = 0; it < 4; ++it) {
        int p = it * 16 + pr;
        *(short8*)(net_out + (t0 + p) * HID + l8) = *(const short8*)&h[p * HS + l8];
    }
}

// ---------- block 0: stage x = pts@Wp+bp (raw bf16), then resnet ----------
// grid (8, 469): batch = blockIdx.x (XCD affinity)
__global__ __launch_bounds__(256, 4) void k_mblock0(
    const float* __restrict__ pts, const float* __restrict__ Wp, const float* __restrict__ bp,
    const short* __restrict__ Wt0, const short* __restrict__ Wts, const short* __restrict__ Wt1,
    const float* __restrict__ b0, const float* __restrict__ b1, short* __restrict__ net)
{
    __shared__ short xs[PB * XS];
    __shared__ float b0s[HID], b1s[HID];
    int tid = threadIdx.x;
    int b  = blockIdx.x;
    int r0 = blockIdx.y * PB;
    if (tid < 128) { b0s[tid] = b0[tid]; b1s[tid] = b1[tid]; }

    int j = tid & 127, half = tid >> 7;
    int col = half * 128 + j;
    float w0 = Wp[col], w1 = Wp[256 + col], w2 = Wp[512 + col];
    float bb = bp[col];
    for (int p = 0; p < PB; ++p) {
        int tt = r0 + p; if (tt > TPTS - 1) tt = TPTS - 1;   // tail rows: duplicate last point
        const float* pp = pts + (b * TPTS + tt) * 3;
        float v = fmaf(pp[2], w2, fmaf(pp[1], w1, fmaf(pp[0], w0, bb)));
        xs[p * XS + col] = f2bf(v);
    }
    __syncthreads();
    resnet_body(xs, b0s, b1s, Wt0, Wts, Wt1, net, b * NPR + r0);
}

// ---------- blocks 1..4: stage x = [net | pooled], then resnet ----------
// grid (8, 469): batch = blockIdx.x (XCD affinity — seg slice per batch fits one XCD L2)
__global__ __launch_bounds__(256, 4) void k_mblock(
    const short* __restrict__ net_in, const short* __restrict__ seg,
    const int* __restrict__ i0, const int* __restrict__ i1, const int* __restrict__ i2,
    const short* __restrict__ Wt0, const short* __restrict__ Wts, const short* __restrict__ Wt1,
    const float* __restrict__ b0, const float* __restrict__ b1, short* __restrict__ net_out)
{
    __shared__ short xs[PB * XS];
    __shared__ float b0s[HID], b1s[HID];
    int tid = threadIdx.x;
    int b  = blockIdx.x;
    int r0 = blockIdx.y * PB;
    if (tid < 128) { b0s[tid] = b0[tid]; b1s[tid] = b1[tid]; }

    int pr = tid >> 4;          // row within group of 16
    int l8 = (tid & 15) * 8;    // short offset of 16B chunk
#pragma unroll
    for (int it = 0; it < 4; ++it) {
        int p = it * 16 + pr;
        int tt = r0 + p;
        int ttc = tt > TPTS - 1 ? TPTS - 1 : tt;   // tail: clamp index reads (rows unused downstream)
        int ib = b * TPTS + ttc;
        int a0 = i0[ib], a1 = i1[ib], a2 = i2[ib];
        // raw net copy (already bf16); wave reads a contiguous 1KB block
        *(short8*)&xs[p * XS + l8] = *(const short8*)(net_in + (b * NPR + tt) * HID + l8);
        // pooled = sum of 3 plane maxima
        short8 s0 = *(const short8*)(seg + ((0 * BATCH + b) * R2 + a0) * HID + l8);
        short8 s1 = *(const short8*)(seg + ((1 * BATCH + b) * R2 + a1) * HID + l8);
        short8 s2 = *(const short8*)(seg + ((2 * BATCH + b) * R2 + a2) * HID + l8);
        short8 pv;
#pragma unroll
        for (int r = 0; r < 8; ++r)
            pv[r] = f2bf(bf2f((unsigned short)s0[r]) + bf2f((unsigned short)s1[r]) + bf2f((unsigned short)s2[r]));
        *(short8*)&xs[p * XS + 128 + l8] = pv;
    }
    __syncthreads();
    resnet_body(xs, b0s, b1s, Wt0, Wts, Wt1, net_out, b * NPR + r0);
}

// ---------- out = (means @ Wc + bc)^T per plane-batch, empty bins -> 0 ----------
// grid (8, 192): batch = blockIdx.x, plane/bin-tile from blockIdx.y
__global__ __launch_bounds__(256) void k_gemmout(
    const short* __restrict__ meanb, const short* __restrict__ Wtc, const float* __restrict__ bc,
    const int* __restrict__ starts, float* __restrict__ out)
{
    __shared__ short bs[64 * HS];      // means bf16 [bin][k]
    __shared__ float tile[128 * 66];   // output f32 [ch][bin]
    __shared__ float bcs[HID];
    __shared__ int   flg[64];
    int tid = threadIdx.x;
    int b = blockIdx.x;
    int plane = blockIdx.y >> 6;
    int pb = plane * BATCH + b;
    int bin0 = (blockIdx.y & 63) * 64;

    if (tid < 128) bcs[tid] = bc[tid];
    if (tid < 64)  flg[tid] = (starts[pb * 4097 + bin0 + tid + 1] > starts[pb * 4097 + bin0 + tid]);
    for (int c8 = tid; c8 < 1024; c8 += 256) {
        int p = c8 >> 4, l = (c8 & 15) * 8;
        *(short8*)&bs[p * HS + l] = *(const short8*)(meanb + (pb * R2 + bin0 + p) * HID + l);
    }
    __syncthreads();

    int lane = tid & 63, wave = tid >> 6;
    int n = lane & 15, quad = lane >> 4;
    int ch0 = wave * 32;
    f32x4 acc[2][4] = {};
    for (int ks = 0; ks < 4; ++ks) {
        int ko = ks * 32 + quad * 8;
        short8 a[2];
#pragma unroll
        for (int c = 0; c < 2; ++c)
            a[c] = *(const short8*)(Wtc + (ch0 + c * 16 + n) * 128 + ko);
#pragma unroll
        for (int p = 0; p < 4; ++p) {
            short8 bh = *(const short8*)&bs[(p * 16 + n) * HS + ko];
#pragma unroll
            for (int c = 0; c < 2; ++c)
                acc[c][p] = __builtin_amdgcn_mfma_f32_16x16x32_bf16(a[c], bh, acc[c][p], 0, 0, 0);
        }
    }
#pragma unroll
    for (int c = 0; c < 2; ++c) {
        int chb = ch0 + c * 16 + quad * 4;
#pragma unroll
        for (int p = 0; p < 4; ++p) {
            int bin = p * 16 + n;
#pragma unroll
            for (int r = 0; r < 4; ++r)
                tile[(chb + r) * 66 + bin] = acc[c][p][r] + bcs[chb + r];
        }
    }
    __syncthreads();

    for (int c4 = tid; c4 < 2048; c4 += 256) {
        int ch = c4 >> 4, b4 = (c4 & 15) * 4;
        float4 o;
        o.x = flg[b4 + 0] ? tile[ch * 66 + b4 + 0] : 0.f;
        o.y = flg[b4 + 1] ? tile[ch * 66 + b4 + 1] : 0.f;
        o.z = flg[b4 + 2] ? tile[ch * 66 + b4 + 2] : 0.f;
        o.w = flg[b4 + 3] ? tile[ch * 66 + b4 + 3] : 0.f;
        *(float4*)(out + (pb * 128 + ch) * R2 + bin0 + b4) = o;
    }
}

extern "C" void kernel_launch(void* const* d_in, const int* in_sizes, int n_in,
                              void* d_out, int out_size, void* d_ws, size_t ws_size,
                              hipStream_t stream) {
    const float* pts  = (const float*)d_in[0];
    const int*   ixz  = (const int*)d_in[1];
    const int*   ixy  = (const int*)d_in[2];
    const int*   iyz  = (const int*)d_in[3];
    const float* Wp   = (const float*)d_in[4];
    const float* bp   = (const float*)d_in[5];
    const float* fc0w = (const float*)d_in[6];
    const float* fc0b = (const float*)d_in[7];
    const float* fc1w = (const float*)d_in[8];
    const float* fc1b = (const float*)d_in[9];
    const float* scw  = (const float*)d_in[10];
    const float* Wc   = (const float*)d_in[11];
    const float* bc   = (const float*)d_in[12];
    float* out = (float*)d_out;

    short* Wt0 = (short*)d_ws;             // 163840
    short* Wts = Wt0 + 163840;             // 163840
    short* Wt1 = Wts + 163840;             // 81920
    short* Wtc = Wt1 + 81920;              // 16384   (total 425984 shorts)
    short* net  = Wtc + 16384;             // 8*30016*128 = 30,736,384 shorts, bf16 (batch-padded)
    short* segb = net + 30736384;          // 12,582,912 shorts, bf16 (pool max / means)
    int* hist   = (int*)(segb + 12582912); // 98304 (doubles as cursor)
    int* starts = hist + 98304;            // 24*4097
    unsigned short* order = (unsigned short*)(starts + 98328); // 720000

    k_prep<<<dim3(640), 256, 0, stream>>>(fc0w, fc1w, scw, Wc, Wt0, Wts, Wt1, Wtc);
    k_fill4<<<dim3(96), 256, 0, stream>>>((float4*)hist, 0.f, 98304 / 4);
    k_hist<<<dim3((NPTS + 255) / 256), 256, 0, stream>>>(ixz, ixy, iyz, hist);
    k_scan<<<dim3(24), 256, 0, stream>>>(hist, starts, hist);
    k_scatter<<<dim3((NPTS + 255) / 256), 256, 0, stream>>>(ixz, ixy, iyz, hist, order);

    k_mblock0<<<dim3(8, NPR / PB), 256, 0, stream>>>(pts, Wp, bp, Wt0, Wts, Wt1, fc0b, fc1b, net);

    for (int r = 1; r < 5; ++r) {
        k_poolmax<<<dim3(8, 3 * R2 / 4), 256, 0, stream>>>(net, starts, order, segb);
        k_mblock<<<dim3(8, NPR / PB), 256, 0, stream>>>(
            net, segb, ixz, ixy, iyz,
            Wt0 + r * 32768, Wts + r * 32768, Wt1 + r * 16384,
            fc0b + r * 128, fc1b + r * 128, net);
    }

    // segment_mean(net@Wc+bc) == segment_mean(net)@Wc+bc  (bin means, then tiny GEMM)
    k_poolmean<<<dim3(8, 3 * R2 / 4), 256, 0, stream>>>(net, starts, order, segb);
    k_gemmout<<<dim3(8, 3 * 64), 256, 0, stream>>>(segb, Wtc, bc, starts, out);
}